// Round 3
// baseline (3514.369 us; speedup 1.0000x reference)
//
#include <hip/hip_runtime.h>
#include <math.h>

// Problem constants
#define BT     4096      // B*T tokens per pass
#define M_TOT  8192      // 2 passes stacked
#define KDIM   768
#define VDIM   50257
#define NBLK   393       // ceil(VDIM/128)
#define KC8    6         // 768 / 128 K-chunks (fp8 path)
#define REWARD_SCALE 0.5
#define DIV_WEIGHT   0.1
#define EPS_COS      1e-8f
#define LOG2E        1.44269504088896340736f

typedef float f32x4 __attribute__((ext_vector_type(4)));
typedef int   i32x4v __attribute__((ext_vector_type(4)));
typedef int   i32x8v __attribute__((ext_vector_type(8)));
union frag8 { i32x8v v8; i32x4v v4[2]; };

// fp8 fragment storage: unit = (128-row blk, k0 of 128, tile of 16 rows)
//   = 2 KB: [h(0,1)][lane(64)][16B], lane -> row = tile*16 + (lane&15),
//   k = (lane>>4)*32 + h*16 + j   (j = byte 0..15)
#define A8_BYTES ((size_t)64 * KC8 * 8 * 2048)    //  6.29 MB
#define W8_BYTES ((size_t)NBLK * KC8 * 8 * 2048)  // 38.6 MB

// ---------------------------------------------------------------------------
// async global->LDS, 16B per lane (wave-uniform base + lane*16 semantics)
// ---------------------------------------------------------------------------
__device__ __forceinline__ void g2l16(const void* g, void* l) {
    __builtin_amdgcn_global_load_lds(
        (const __attribute__((address_space(1))) unsigned int*)g,
        (__attribute__((address_space(3))) unsigned int*)l,
        16, 0, 0);
}

// ---------------------------------------------------------------------------
// Converters: fp32 -> fp8 e4m3 (OCP), pre-swizzled into MFMA fragment order.
// W additionally scaled by log2(e) so GEMM logits come out base-2.
// Each block handles 128 rows x 64 K-cols (half of a K=128 chunk).
// ---------------------------------------------------------------------------
__global__ __launch_bounds__(256)
void convert_A8_kernel(const float* __restrict__ p2, const float* __restrict__ p3,
                       unsigned char* __restrict__ A8)
{
    __shared__ float Ls[128][65];
    const int mb = blockIdx.x;             // 0..63
    const int kc = blockIdx.y;             // 0..11 (64-col half-chunks)
    const int tid = threadIdx.x;
    const int colBase = kc * 64;

#pragma unroll
    for (int p = 0; p < 8; ++p) {
        int i = p * 1024 + tid * 4;
        int r = i >> 6;
        int c = i & 63;
        int m = mb * 128 + r;
        const float* src = (m < BT) ? (p2 + (size_t)m * KDIM)
                                    : (p3 + (size_t)(m - BT) * KDIM);
        float4 v = *(const float4*)(src + colBase + c);
        Ls[r][c + 0] = v.x; Ls[r][c + 1] = v.y;
        Ls[r][c + 2] = v.z; Ls[r][c + 3] = v.w;
    }
    __syncthreads();

    const int k0 = kc >> 1;
    const int gBase = (kc & 1) * 2;        // lane-group base (0 or 2)
#pragma unroll
    for (int p = 0; p < 2; ++p) {
        int f    = tid + p * 256;          // 0..511
        int tile = f >> 6;
        int r6   = f & 63;
        int lp   = r6 >> 1;                // 0..31
        int h    = r6 & 1;
        int lane = gBase * 16 + lp;        // output lane 0..63
        int row  = tile * 16 + (lp & 15);
        int cloc = (lp >> 4) * 32 + h * 16;
        unsigned int d[4];
#pragma unroll
        for (int q = 0; q < 4; ++q) {
            int dd = 0;
            dd = __builtin_amdgcn_cvt_pk_fp8_f32(Ls[row][cloc + q*4 + 0],
                                                 Ls[row][cloc + q*4 + 1], dd, false);
            dd = __builtin_amdgcn_cvt_pk_fp8_f32(Ls[row][cloc + q*4 + 2],
                                                 Ls[row][cloc + q*4 + 3], dd, true);
            d[q] = (unsigned int)dd;
        }
        size_t off = ((size_t)(mb * KC8 + k0) * 8 + tile) * 2048
                   + (size_t)h * 1024 + (size_t)lane * 16;
        *(uint4*)(A8 + off) = make_uint4(d[0], d[1], d[2], d[3]);
    }
}

__global__ __launch_bounds__(256)
void convert_W8_kernel(const float* __restrict__ W, unsigned char* __restrict__ W8)
{
    __shared__ float Ls[128][65];
    const int nb = blockIdx.x;             // 0..392
    const int kc = blockIdx.y;             // 0..11
    const int tid = threadIdx.x;
    const int colBase = kc * 64;

#pragma unroll
    for (int p = 0; p < 8; ++p) {
        int i = p * 1024 + tid * 4;
        int r = i >> 6;
        int c = i & 63;
        int v = nb * 128 + r;
        float4 val = make_float4(0.f, 0.f, 0.f, 0.f);
        if (v < VDIM) val = *(const float4*)(W + (size_t)v * KDIM + colBase + c);
        Ls[r][c + 0] = val.x * LOG2E; Ls[r][c + 1] = val.y * LOG2E;
        Ls[r][c + 2] = val.z * LOG2E; Ls[r][c + 3] = val.w * LOG2E;
    }
    __syncthreads();

    const int k0 = kc >> 1;
    const int gBase = (kc & 1) * 2;
#pragma unroll
    for (int p = 0; p < 2; ++p) {
        int f    = tid + p * 256;
        int tile = f >> 6;
        int r6   = f & 63;
        int lp   = r6 >> 1;
        int h    = r6 & 1;
        int lane = gBase * 16 + lp;
        int row  = tile * 16 + (lp & 15);
        int cloc = (lp >> 4) * 32 + h * 16;
        unsigned int d[4];
#pragma unroll
        for (int q = 0; q < 4; ++q) {
            int dd = 0;
            dd = __builtin_amdgcn_cvt_pk_fp8_f32(Ls[row][cloc + q*4 + 0],
                                                 Ls[row][cloc + q*4 + 1], dd, false);
            dd = __builtin_amdgcn_cvt_pk_fp8_f32(Ls[row][cloc + q*4 + 2],
                                                 Ls[row][cloc + q*4 + 3], dd, true);
            d[q] = (unsigned int)dd;
        }
        size_t off = ((size_t)(nb * KC8 + k0) * 8 + tile) * 2048
                   + (size_t)h * 1024 + (size_t)lane * 16;
        *(uint4*)(W8 + off) = make_uint4(d[0], d[1], d[2], d[3]);
    }
}

// ---------------------------------------------------------------------------
// Main GEMM (fp8 MX, scales = 1.0): 128x128 tile, 256 threads (4 waves 2x2),
// wave tile 64x64, K-chunks of 128 via mfma_scale_f32_16x16x128_f8f6f4.
// Same verified structure/pipe-split as the 681us f16 baseline:
//   A: global_load_lds double-buffered (32 KB LDS), per-k0 __syncthreads.
//   B: direct global->VGPR, single-buffered (32 regs), next-k0 prefetch
//      issued after last use, drained by the barrier.
// All pipe demands are ~half of the f16 baseline; MFMA floor 305->136 us.
// ---------------------------------------------------------------------------
__global__ __launch_bounds__(256, 4)
void gemm_fp8_kernel(const unsigned char* __restrict__ A8,
                     const unsigned char* __restrict__ W8,
                     double* __restrict__ g_sumexp)
{
    __shared__ __align__(16) unsigned char As[2][16384];   // 32 KB
    __shared__ float rowsum[128];

    const int tid  = threadIdx.x;
    const int lane = tid & 63;
    const int w    = tid >> 6;       // 0..3
    const int wm   = w >> 1;         // 0..1
    const int wn   = w & 1;          // 0..1
    const int mb   = blockIdx.x;     // 0..63
    const int nb   = blockIdx.y;     // 0..392

    if (tid < 128) rowsum[tid] = 0.0f;

    f32x4 acc[4][4];
#pragma unroll
    for (int i = 0; i < 4; ++i)
#pragma unroll
        for (int j = 0; j < 4; ++j) acc[i][j] = (f32x4)0.0f;

    const unsigned char* Agl = A8 + (size_t)mb * KC8 * 8 * 2048 + (size_t)lane * 16;
    const unsigned char* Bgl = W8 + ((size_t)nb * KC8 * 8 + (size_t)wn * 4) * 2048
                                  + (size_t)lane * 16;
    unsigned char* sDst = &As[0][0] + (size_t)(2 * w) * 2048 + (size_t)lane * 16;
    const unsigned char* aRd = &As[0][0] + (size_t)(wm * 4) * 2048 + (size_t)lane * 16;

    // wave w stages fragment-units {2w, 2w+1} (4 x g2l16 per wave per k0)
#define STAGE8(k0_, buf_)                                                     \
    {                                                                         \
        _Pragma("unroll")                                                     \
        for (int uu = 0; uu < 2; ++uu)                                        \
            _Pragma("unroll")                                                 \
            for (int hh = 0; hh < 2; ++hh)                                    \
                g2l16(Agl + ((size_t)(k0_) * 8 + 2 * w + uu) * 2048           \
                          + (size_t)hh * 1024,                                \
                      sDst + (size_t)(buf_) * 16384 + (size_t)uu * 2048       \
                           + (size_t)hh * 1024);                              \
    }

    frag8 b[4];
#define LOADB(k0_)                                                            \
    {                                                                         \
        _Pragma("unroll")                                                     \
        for (int nt = 0; nt < 4; ++nt) {                                      \
            b[nt].v4[0] = *(const i32x4v*)(Bgl                                \
                + ((size_t)(k0_) * 8 + nt) * 2048);                           \
            b[nt].v4[1] = *(const i32x4v*)(Bgl                                \
                + ((size_t)(k0_) * 8 + nt) * 2048 + 1024);                    \
        }                                                                     \
    }

    STAGE8(0, 0);
    LOADB(0);

#pragma unroll
    for (int k0 = 0; k0 < KC8; ++k0) {
        const int buf = k0 & 1;
        __syncthreads();                       // As[buf] + b[] resident
        if (k0 + 1 < KC8) STAGE8(k0 + 1, buf ^ 1);
#pragma unroll
        for (int tm = 0; tm < 4; ++tm) {
            frag8 a;
            a.v4[0] = *(const i32x4v*)(aRd + (size_t)buf * 16384 + (size_t)tm * 2048);
            a.v4[1] = *(const i32x4v*)(aRd + (size_t)buf * 16384 + (size_t)tm * 2048 + 1024);
#pragma unroll
            for (int nt = 0; nt < 4; ++nt)
                acc[tm][nt] = __builtin_amdgcn_mfma_scale_f32_16x16x128_f8f6f4(
                    a.v8, b[nt].v8, acc[tm][nt],
                    0 /*cbsz: A=fp8 e4m3*/, 0 /*blgp: B=fp8 e4m3*/,
                    0, 0x7F7F7F7F /*scale_a = 1.0*/,
                    0, 0x7F7F7F7F /*scale_b = 1.0*/);
        }
        if (k0 + 1 < KC8) LOADB(k0 + 1);       // prefetch next B after last use
    }
#undef STAGE8
#undef LOADB

    // --- epilogue: exp2 (logits pre-scaled by log2e), per-row reduce ---
    __syncthreads();
    const int colBase = nb * 128 + wn * 64;
    const int quad = lane >> 4;
    const int cidx = lane & 15;
#pragma unroll
    for (int tm = 0; tm < 4; ++tm) {
#pragma unroll
        for (int r = 0; r < 4; ++r) {
            float s = 0.0f;
#pragma unroll
            for (int tn = 0; tn < 4; ++tn) {
                int col = colBase + tn * 16 + cidx;
                if (col < VDIM) s += __builtin_amdgcn_exp2f(acc[tm][tn][r]);
            }
            s += __shfl_xor(s, 1);
            s += __shfl_xor(s, 2);
            s += __shfl_xor(s, 4);
            s += __shfl_xor(s, 8);
            if (cidx == 0) {
                int row = wm * 64 + tm * 16 + quad * 4 + r;
                atomicAdd(&rowsum[row], s);
            }
        }
    }
    __syncthreads();
    if (tid < 128) {
        atomicAdd(&g_sumexp[(size_t)mb * 128 + tid], (double)rowsum[tid]);
    }
}

// ---------------------------------------------------------------------------
// Fallback fp32 GEMM (round-2 kernel) if workspace is too small.
// ---------------------------------------------------------------------------
#define BM 128
#define BN 128
#define BK 16
#define LDPAD 4
__global__ __launch_bounds__(256)
void logits_expsum_kernel(const float* __restrict__ p2,
                          const float* __restrict__ p3,
                          const float* __restrict__ W,
                          double* __restrict__ g_sumexp)
{
    __shared__ float As[BK][BM + LDPAD];
    __shared__ float Bsh[BK][BN + LDPAD];
    __shared__ float rowsum[BM];

    const int tid     = threadIdx.x;
    const int rowBase = blockIdx.y * BM;
    const int colBase = blockIdx.x * BN;

    if (tid < BM) rowsum[tid] = 0.0f;

    float acc[8][8];
#pragma unroll
    for (int i = 0; i < 8; ++i)
#pragma unroll
        for (int j = 0; j < 8; ++j) acc[i][j] = 0.0f;

    const int ty = tid >> 4;
    const int tx = tid & 15;
    const int r0 = ty * 8;
    const int c0 = tx * 4;

    for (int k0 = 0; k0 < KDIM; k0 += BK) {
        __syncthreads();
#pragma unroll
        for (int l = 0; l < 2; ++l) {
            int id  = tid + l * 256;
            int row = id >> 2;
            int kq  = id & 3;
            int m   = rowBase + row;
            const float* src = (m < BT) ? (p2 + (size_t)m * KDIM)
                                        : (p3 + (size_t)(m - BT) * KDIM);
            float4 v = *(const float4*)(src + k0 + kq * 4);
            As[kq * 4 + 0][row] = v.x;
            As[kq * 4 + 1][row] = v.y;
            As[kq * 4 + 2][row] = v.z;
            As[kq * 4 + 3][row] = v.w;
        }
#pragma unroll
        for (int l = 0; l < 2; ++l) {
            int id  = tid + l * 256;
            int row = id >> 2;
            int kq  = id & 3;
            int c   = colBase + row;
            int cs  = (c < VDIM) ? c : (VDIM - 1);
            float4 v = *(const float4*)(W + (size_t)cs * KDIM + k0 + kq * 4);
            Bsh[kq * 4 + 0][row] = v.x;
            Bsh[kq * 4 + 1][row] = v.y;
            Bsh[kq * 4 + 2][row] = v.z;
            Bsh[kq * 4 + 3][row] = v.w;
        }
        __syncthreads();
#pragma unroll
        for (int kk = 0; kk < BK; ++kk) {
            float a[8], bb[8];
            *(float4*)&a[0]  = *(const float4*)&As[kk][r0];
            *(float4*)&a[4]  = *(const float4*)&As[kk][r0 + 4];
            *(float4*)&bb[0] = *(const float4*)&Bsh[kk][c0];
            *(float4*)&bb[4] = *(const float4*)&Bsh[kk][64 + c0];
#pragma unroll
            for (int i = 0; i < 8; ++i)
#pragma unroll
                for (int j = 0; j < 8; ++j)
                    acc[i][j] = fmaf(a[i], bb[j], acc[i][j]);
        }
    }

    __syncthreads();
#pragma unroll
    for (int i = 0; i < 8; ++i) {
        float s = 0.0f;
#pragma unroll
        for (int j = 0; j < 8; ++j) {
            int c = colBase + ((j < 4) ? (c0 + j) : (64 + c0 + (j - 4)));
            if (c < VDIM) s += expf(acc[i][j]);
        }
        atomicAdd(&rowsum[r0 + i], s);
    }
    __syncthreads();
    if (tid < BM) {
        atomicAdd(&g_sumexp[rowBase + tid], (double)rowsum[tid]);
    }
}

// ---------------------------------------------------------------------------
// Kernel 2: per token — exact fp32 target logits + cosine.  NO atomics:
// writes per-token values; reduced by final_scalar_kernel.
// tokvals[t] = {nll2, nll3, cos, valid}
// ---------------------------------------------------------------------------
__global__ __launch_bounds__(256)
void finalize_tokens_kernel(const float* __restrict__ p2,
                            const float* __restrict__ p3,
                            const float* __restrict__ W,
                            const int*   __restrict__ targets,
                            const double* __restrict__ g_sumexp,
                            double* __restrict__ tokvals)
{
    const int t   = blockIdx.x;
    const int tid = threadIdx.x;
    const int tg  = targets[t];
    const bool valid = (tg >= 0);
    const float* w = W + (size_t)(valid ? tg : 0) * KDIM;
    const float* a = p2 + (size_t)t * KDIM;
    const float* b = p3 + (size_t)t * KDIM;

    float s22 = 0.f, s33 = 0.f, s23 = 0.f, s2w = 0.f, s3w = 0.f;
    for (int i = tid; i < KDIM; i += 256) {
        float x = a[i], y = b[i], ww = w[i];
        s22 = fmaf(x, x, s22);
        s33 = fmaf(y, y, s33);
        s23 = fmaf(x, y, s23);
        s2w = fmaf(x, ww, s2w);
        s3w = fmaf(y, ww, s3w);
    }
#pragma unroll
    for (int off = 32; off > 0; off >>= 1) {
        s22 += __shfl_down(s22, off);
        s33 += __shfl_down(s33, off);
        s23 += __shfl_down(s23, off);
        s2w += __shfl_down(s2w, off);
        s3w += __shfl_down(s3w, off);
    }
    __shared__ float sm[5][4];
    const int wv = tid >> 6, lane = tid & 63;
    if (lane == 0) {
        sm[0][wv] = s22; sm[1][wv] = s33; sm[2][wv] = s23;
        sm[3][wv] = s2w; sm[4][wv] = s3w;
    }
    __syncthreads();
    if (tid == 0) {
        float S22 = sm[0][0] + sm[0][1] + sm[0][2] + sm[0][3];
        float S33 = sm[1][0] + sm[1][1] + sm[1][2] + sm[1][3];
        float S23 = sm[2][0] + sm[2][1] + sm[2][2] + sm[2][3];
        float S2w = sm[3][0] + sm[3][1] + sm[3][2] + sm[3][3];
        float S3w = sm[4][0] + sm[4][1] + sm[4][2] + sm[4][3];

        float n2 = fmaxf(sqrtf(S22), EPS_COS);
        float n3 = fmaxf(sqrtf(S33), EPS_COS);

        double4 out;
        out.x = valid ? (log(g_sumexp[t])      - (double)S2w) : 0.0;
        out.y = valid ? (log(g_sumexp[BT + t]) - (double)S3w) : 0.0;
        out.z = (double)(S23 / (n2 * n3));
        out.w = valid ? 1.0 : 0.0;
        *(double4*)(tokvals + 4 * (size_t)t) = out;
    }
}

// ---------------------------------------------------------------------------
// Kernel 3: reduce tokvals -> output scalar (one 1024-thread block).
// ---------------------------------------------------------------------------
__global__ __launch_bounds__(1024)
void final_scalar_kernel(const double* __restrict__ tokvals,
                         float* __restrict__ out)
{
    const int tid = threadIdx.x;
    double s0 = 0.0, s1 = 0.0, s2 = 0.0, s3 = 0.0;
    for (int t = tid; t < BT; t += 1024) {
        double4 v = *(const double4*)(tokvals + 4 * (size_t)t);
        s0 += v.x; s1 += v.y; s2 += v.z; s3 += v.w;
    }
#pragma unroll
    for (int off = 32; off > 0; off >>= 1) {
        s0 += __shfl_down(s0, off);
        s1 += __shfl_down(s1, off);
        s2 += __shfl_down(s2, off);
        s3 += __shfl_down(s3, off);
    }
    __shared__ double sm[4][16];
    const int wv = tid >> 6, lane = tid & 63;
    if (lane == 0) { sm[0][wv] = s0; sm[1][wv] = s1; sm[2][wv] = s2; sm[3][wv] = s3; }
    __syncthreads();
    if (tid == 0) {
        double S0 = 0, S1 = 0, S2 = 0, S3 = 0;
#pragma unroll
        for (int i = 0; i < 16; ++i) { S0 += sm[0][i]; S1 += sm[1][i]; S2 += sm[2][i]; S3 += sm[3][i]; }
        double cnt = (S3 > 0.0) ? S3 : 1.0;
        double loss_p2 = S0 / cnt;
        double loss_p3 = S1 / cnt;
        double reward_loss = -REWARD_SCALE * (loss_p2 - loss_p3);
        double divergence  =  DIV_WEIGHT * (S2 / (double)BT);
        out[0] = (float)(reward_loss + divergence);
    }
}

// ---------------------------------------------------------------------------
extern "C" void kernel_launch(void* const* d_in, const int* in_sizes, int n_in,
                              void* d_out, int out_size, void* d_ws, size_t ws_size,
                              hipStream_t stream)
{
    const float* p2  = (const float*)d_in[0];   // [2,2048,768] fp32
    const float* p3  = (const float*)d_in[1];   // [2,2048,768] fp32
    const float* W   = (const float*)d_in[2];   // [50257,768] fp32
    const int*   tgt = (const int*)d_in[3];     // [2,2048]

    double* g_sumexp = (double*)d_ws;                    // 8192 doubles (64 KB)
    double* tokvals  = g_sumexp + M_TOT;                 // 16384 doubles (128 KB)
    char*   fragbase = (char*)d_ws + 196608;

    hipMemsetAsync(d_ws, 0, 65536, stream);   // g_sumexp only

    const size_t need = 196608 + A8_BYTES + W8_BYTES;    // ~45 MB
    if (ws_size >= need) {
        unsigned char* A8 = (unsigned char*)fragbase;
        unsigned char* W8 = A8 + A8_BYTES;

        convert_A8_kernel<<<dim3(64, 12), dim3(256), 0, stream>>>(p2, p3, A8);
        convert_W8_kernel<<<dim3(NBLK, 12), dim3(256), 0, stream>>>(W, W8);
        // grid.x = mb fast: co-resident blocks share mb (A L1/L2-hot) and
        // spread nb within an XCD (B slices L2-resident).
        gemm_fp8_kernel<<<dim3(64, NBLK), dim3(256), 0, stream>>>(A8, W8, g_sumexp);
    } else {
        logits_expsum_kernel<<<dim3(NBLK, 64), dim3(256), 0, stream>>>(p2, p3, W, g_sumexp);
    }

    finalize_tokens_kernel<<<dim3(BT), dim3(256), 0, stream>>>(
        p2, p3, W, tgt, g_sumexp, tokvals);

    final_scalar_kernel<<<dim3(1), dim3(1024), 0, stream>>>(tokvals, (float*)d_out);
}

// Round 4
// 3414.195 us; speedup vs baseline: 1.0293x; 1.0293x over previous
//
#include <hip/hip_runtime.h>
#include <math.h>

// Problem constants
#define BT     4096      // B*T tokens per pass
#define M_TOT  8192      // 2 passes stacked
#define VDIM   50257
#define KDIM   768
#define NBLK   393       // ceil(VDIM/128)
#define KC8    6         // 768 / 128 K-chunks (fp8 path)
#define REWARD_SCALE 0.5
#define DIV_WEIGHT   0.1
#define EPS_COS      1e-8f
#define LOG2E        1.44269504088896340736f

typedef float f32x4 __attribute__((ext_vector_type(4)));
typedef int   i32x4v __attribute__((ext_vector_type(4)));
typedef int   i32x8v __attribute__((ext_vector_type(8)));
// register-only concat of two 16B halves into one 32B MFMA operand
#define CAT8(lo_, hi_) __builtin_shufflevector((lo_), (hi_), 0, 1, 2, 3, 4, 5, 6, 7)

// fp8 fragment storage: unit = (128-row blk, k0 of 128, tile of 16 rows)
//   = 2 KB: [h(0,1)][lane(64)][16B], lane -> row = tile*16 + (lane&15),
//   k = (lane>>4)*32 + h*16 + j   (j = byte 0..15)
#define A8_BYTES ((size_t)64 * KC8 * 8 * 2048)    //  6.29 MB
#define W8_BYTES ((size_t)NBLK * KC8 * 8 * 2048)  // 38.6 MB

// ---------------------------------------------------------------------------
// async global->LDS, 16B per lane (wave-uniform base + lane*16 semantics)
// ---------------------------------------------------------------------------
__device__ __forceinline__ void g2l16(const void* g, void* l) {
    __builtin_amdgcn_global_load_lds(
        (const __attribute__((address_space(1))) unsigned int*)g,
        (__attribute__((address_space(3))) unsigned int*)l,
        16, 0, 0);
}

// ---------------------------------------------------------------------------
// Converters: fp32 -> fp8 e4m3 (OCP), pre-swizzled into MFMA fragment order.
// W additionally scaled by log2(e) so GEMM logits come out base-2.
// Each block handles 128 rows x 64 K-cols (half of a K=128 chunk).
// ---------------------------------------------------------------------------
__global__ __launch_bounds__(256)
void convert_A8_kernel(const float* __restrict__ p2, const float* __restrict__ p3,
                       unsigned char* __restrict__ A8)
{
    __shared__ float Ls[128][65];
    const int mb = blockIdx.x;             // 0..63
    const int kc = blockIdx.y;             // 0..11 (64-col half-chunks)
    const int tid = threadIdx.x;
    const int colBase = kc * 64;

#pragma unroll
    for (int p = 0; p < 8; ++p) {
        int i = p * 1024 + tid * 4;
        int r = i >> 6;
        int c = i & 63;
        int m = mb * 128 + r;
        const float* src = (m < BT) ? (p2 + (size_t)m * KDIM)
                                    : (p3 + (size_t)(m - BT) * KDIM);
        float4 v = *(const float4*)(src + colBase + c);
        Ls[r][c + 0] = v.x; Ls[r][c + 1] = v.y;
        Ls[r][c + 2] = v.z; Ls[r][c + 3] = v.w;
    }
    __syncthreads();

    const int k0 = kc >> 1;
    const int gBase = (kc & 1) * 2;        // lane-group base (0 or 2)
#pragma unroll
    for (int p = 0; p < 2; ++p) {
        int f    = tid + p * 256;          // 0..511
        int tile = f >> 6;
        int r6   = f & 63;
        int lp   = r6 >> 1;                // 0..31
        int h    = r6 & 1;
        int lane = gBase * 16 + lp;        // output lane 0..63
        int row  = tile * 16 + (lp & 15);
        int cloc = (lp >> 4) * 32 + h * 16;
        unsigned int d[4];
#pragma unroll
        for (int q = 0; q < 4; ++q) {
            int dd = 0;
            dd = __builtin_amdgcn_cvt_pk_fp8_f32(Ls[row][cloc + q*4 + 0],
                                                 Ls[row][cloc + q*4 + 1], dd, false);
            dd = __builtin_amdgcn_cvt_pk_fp8_f32(Ls[row][cloc + q*4 + 2],
                                                 Ls[row][cloc + q*4 + 3], dd, true);
            d[q] = (unsigned int)dd;
        }
        size_t off = ((size_t)(mb * KC8 + k0) * 8 + tile) * 2048
                   + (size_t)h * 1024 + (size_t)lane * 16;
        *(uint4*)(A8 + off) = make_uint4(d[0], d[1], d[2], d[3]);
    }
}

__global__ __launch_bounds__(256)
void convert_W8_kernel(const float* __restrict__ W, unsigned char* __restrict__ W8)
{
    __shared__ float Ls[128][65];
    const int nb = blockIdx.x;             // 0..392
    const int kc = blockIdx.y;             // 0..11
    const int tid = threadIdx.x;
    const int colBase = kc * 64;

#pragma unroll
    for (int p = 0; p < 8; ++p) {
        int i = p * 1024 + tid * 4;
        int r = i >> 6;
        int c = i & 63;
        int v = nb * 128 + r;
        float4 val = make_float4(0.f, 0.f, 0.f, 0.f);
        if (v < VDIM) val = *(const float4*)(W + (size_t)v * KDIM + colBase + c);
        Ls[r][c + 0] = val.x * LOG2E; Ls[r][c + 1] = val.y * LOG2E;
        Ls[r][c + 2] = val.z * LOG2E; Ls[r][c + 3] = val.w * LOG2E;
    }
    __syncthreads();

    const int k0 = kc >> 1;
    const int gBase = (kc & 1) * 2;
#pragma unroll
    for (int p = 0; p < 2; ++p) {
        int f    = tid + p * 256;
        int tile = f >> 6;
        int r6   = f & 63;
        int lp   = r6 >> 1;
        int h    = r6 & 1;
        int lane = gBase * 16 + lp;
        int row  = tile * 16 + (lp & 15);
        int cloc = (lp >> 4) * 32 + h * 16;
        unsigned int d[4];
#pragma unroll
        for (int q = 0; q < 4; ++q) {
            int dd = 0;
            dd = __builtin_amdgcn_cvt_pk_fp8_f32(Ls[row][cloc + q*4 + 0],
                                                 Ls[row][cloc + q*4 + 1], dd, false);
            dd = __builtin_amdgcn_cvt_pk_fp8_f32(Ls[row][cloc + q*4 + 2],
                                                 Ls[row][cloc + q*4 + 3], dd, true);
            d[q] = (unsigned int)dd;
        }
        size_t off = ((size_t)(nb * KC8 + k0) * 8 + tile) * 2048
                   + (size_t)h * 1024 + (size_t)lane * 16;
        *(uint4*)(W8 + off) = make_uint4(d[0], d[1], d[2], d[3]);
    }
}

// ---------------------------------------------------------------------------
// Main GEMM (fp8 MX, scales = 1.0): 128x128 tile, 256 threads (4 waves 2x2),
// wave tile 64x64, K-chunks of 128 via mfma_scale_f32_16x16x128_f8f6f4.
// Same verified structure/pipe-split as the 681us f16 baseline:
//   A: global_load_lds double-buffered (32 KB LDS), per-k0 __syncthreads.
//   B: direct global->VGPR, single-buffered halves (bl/bh: 32 VGPR),
//      next-k0 prefetch issued after last use, drained by the barrier.
// R3 post-mortem: the frag8 UNION forced b[]/a into scratch (6.5 GB spill
// writes, MfmaUtil 4%).  Fixed: named i32x4v halves + __builtin_shufflevector
// concat (register-only, all-static indices; rule #20).
// ---------------------------------------------------------------------------
__global__ __launch_bounds__(256, 4)
void gemm_fp8_kernel(const unsigned char* __restrict__ A8,
                     const unsigned char* __restrict__ W8,
                     double* __restrict__ g_sumexp)
{
    __shared__ __align__(16) unsigned char As[2][16384];   // 32 KB
    __shared__ float rowsum[128];

    const int tid  = threadIdx.x;
    const int lane = tid & 63;
    const int w    = tid >> 6;       // 0..3
    const int wm   = w >> 1;         // 0..1
    const int wn   = w & 1;          // 0..1
    const int mb   = blockIdx.x;     // 0..63
    const int nb   = blockIdx.y;     // 0..392

    if (tid < 128) rowsum[tid] = 0.0f;

    f32x4 acc[4][4];
#pragma unroll
    for (int i = 0; i < 4; ++i)
#pragma unroll
        for (int j = 0; j < 4; ++j) acc[i][j] = (f32x4)0.0f;

    const unsigned char* Agl = A8 + (size_t)mb * KC8 * 8 * 2048 + (size_t)lane * 16;
    const unsigned char* Bgl = W8 + ((size_t)nb * KC8 * 8 + (size_t)wn * 4) * 2048
                                  + (size_t)lane * 16;
    unsigned char* sDst = &As[0][0] + (size_t)(2 * w) * 2048 + (size_t)lane * 16;
    const unsigned char* aRd = &As[0][0] + (size_t)(wm * 4) * 2048 + (size_t)lane * 16;

    // wave w stages fragment-units {2w, 2w+1} (4 x g2l16 per wave per k0)
#define STAGE8(k0_, buf_)                                                     \
    {                                                                         \
        _Pragma("unroll")                                                     \
        for (int uu = 0; uu < 2; ++uu)                                        \
            _Pragma("unroll")                                                 \
            for (int hh = 0; hh < 2; ++hh)                                    \
                g2l16(Agl + ((size_t)(k0_) * 8 + 2 * w + uu) * 2048           \
                          + (size_t)hh * 1024,                                \
                      sDst + (size_t)(buf_) * 16384 + (size_t)uu * 2048       \
                           + (size_t)hh * 1024);                              \
    }

    i32x4v bl[4], bh[4];                  // B halves, register-resident
#define LOADB(k0_)                                                            \
    {                                                                         \
        _Pragma("unroll")                                                     \
        for (int nt = 0; nt < 4; ++nt) {                                      \
            bl[nt] = *(const i32x4v*)(Bgl + ((size_t)(k0_) * 8 + nt) * 2048); \
            bh[nt] = *(const i32x4v*)(Bgl + ((size_t)(k0_) * 8 + nt) * 2048   \
                                          + 1024);                            \
        }                                                                     \
    }

    STAGE8(0, 0);
    LOADB(0);

#pragma unroll
    for (int k0 = 0; k0 < KC8; ++k0) {
        const int buf = k0 & 1;
        __syncthreads();                       // As[buf] + b[] resident
        if (k0 + 1 < KC8) STAGE8(k0 + 1, buf ^ 1);
#pragma unroll
        for (int tm = 0; tm < 4; ++tm) {
            i32x4v al = *(const i32x4v*)(aRd + (size_t)buf * 16384
                                             + (size_t)tm * 2048);
            i32x4v ah = *(const i32x4v*)(aRd + (size_t)buf * 16384
                                             + (size_t)tm * 2048 + 1024);
            i32x8v a8 = CAT8(al, ah);
#pragma unroll
            for (int nt = 0; nt < 4; ++nt)
                acc[tm][nt] = __builtin_amdgcn_mfma_scale_f32_16x16x128_f8f6f4(
                    a8, CAT8(bl[nt], bh[nt]), acc[tm][nt],
                    0 /*cbsz: A=fp8 e4m3*/, 0 /*blgp: B=fp8 e4m3*/,
                    0, 0x7F7F7F7F /*scale_a = 1.0*/,
                    0, 0x7F7F7F7F /*scale_b = 1.0*/);
        }
        if (k0 + 1 < KC8) LOADB(k0 + 1);       // prefetch next B after last use
    }
#undef STAGE8
#undef LOADB

    // --- epilogue: exp2 (logits pre-scaled by log2e), per-row reduce ---
    __syncthreads();
    const int colBase = nb * 128 + wn * 64;
    const int quad = lane >> 4;
    const int cidx = lane & 15;
#pragma unroll
    for (int tm = 0; tm < 4; ++tm) {
#pragma unroll
        for (int r = 0; r < 4; ++r) {
            float s = 0.0f;
#pragma unroll
            for (int tn = 0; tn < 4; ++tn) {
                int col = colBase + tn * 16 + cidx;
                if (col < VDIM) s += __builtin_amdgcn_exp2f(acc[tm][tn][r]);
            }
            s += __shfl_xor(s, 1);
            s += __shfl_xor(s, 2);
            s += __shfl_xor(s, 4);
            s += __shfl_xor(s, 8);
            if (cidx == 0) {
                int row = wm * 64 + tm * 16 + quad * 4 + r;
                atomicAdd(&rowsum[row], s);
            }
        }
    }
    __syncthreads();
    if (tid < 128) {
        atomicAdd(&g_sumexp[(size_t)mb * 128 + tid], (double)rowsum[tid]);
    }
}

// ---------------------------------------------------------------------------
// Fallback fp32 GEMM (round-2 kernel) if workspace is too small.
// ---------------------------------------------------------------------------
#define BM 128
#define BN 128
#define BK 16
#define LDPAD 4
__global__ __launch_bounds__(256)
void logits_expsum_kernel(const float* __restrict__ p2,
                          const float* __restrict__ p3,
                          const float* __restrict__ W,
                          double* __restrict__ g_sumexp)
{
    __shared__ float As[BK][BM + LDPAD];
    __shared__ float Bsh[BK][BN + LDPAD];
    __shared__ float rowsum[BM];

    const int tid     = threadIdx.x;
    const int rowBase = blockIdx.y * BM;
    const int colBase = blockIdx.x * BN;

    if (tid < BM) rowsum[tid] = 0.0f;

    float acc[8][8];
#pragma unroll
    for (int i = 0; i < 8; ++i)
#pragma unroll
        for (int j = 0; j < 8; ++j) acc[i][j] = 0.0f;

    const int ty = tid >> 4;
    const int tx = tid & 15;
    const int r0 = ty * 8;
    const int c0 = tx * 4;

    for (int k0 = 0; k0 < KDIM; k0 += BK) {
        __syncthreads();
#pragma unroll
        for (int l = 0; l < 2; ++l) {
            int id  = tid + l * 256;
            int row = id >> 2;
            int kq  = id & 3;
            int m   = rowBase + row;
            const float* src = (m < BT) ? (p2 + (size_t)m * KDIM)
                                        : (p3 + (size_t)(m - BT) * KDIM);
            float4 v = *(const float4*)(src + k0 + kq * 4);
            As[kq * 4 + 0][row] = v.x;
            As[kq * 4 + 1][row] = v.y;
            As[kq * 4 + 2][row] = v.z;
            As[kq * 4 + 3][row] = v.w;
        }
#pragma unroll
        for (int l = 0; l < 2; ++l) {
            int id  = tid + l * 256;
            int row = id >> 2;
            int kq  = id & 3;
            int c   = colBase + row;
            int cs  = (c < VDIM) ? c : (VDIM - 1);
            float4 v = *(const float4*)(W + (size_t)cs * KDIM + k0 + kq * 4);
            Bsh[kq * 4 + 0][row] = v.x;
            Bsh[kq * 4 + 1][row] = v.y;
            Bsh[kq * 4 + 2][row] = v.z;
            Bsh[kq * 4 + 3][row] = v.w;
        }
        __syncthreads();
#pragma unroll
        for (int kk = 0; kk < BK; ++kk) {
            float a[8], bb[8];
            *(float4*)&a[0]  = *(const float4*)&As[kk][r0];
            *(float4*)&a[4]  = *(const float4*)&As[kk][r0 + 4];
            *(float4*)&bb[0] = *(const float4*)&Bsh[kk][c0];
            *(float4*)&bb[4] = *(const float4*)&Bsh[kk][64 + c0];
#pragma unroll
            for (int i = 0; i < 8; ++i)
#pragma unroll
                for (int j = 0; j < 8; ++j)
                    acc[i][j] = fmaf(a[i], bb[j], acc[i][j]);
        }
    }

    __syncthreads();
#pragma unroll
    for (int i = 0; i < 8; ++i) {
        float s = 0.0f;
#pragma unroll
        for (int j = 0; j < 8; ++j) {
            int c = colBase + ((j < 4) ? (c0 + j) : (64 + c0 + (j - 4)));
            if (c < VDIM) s += expf(acc[i][j]);
        }
        atomicAdd(&rowsum[r0 + i], s);
    }
    __syncthreads();
    if (tid < BM) {
        atomicAdd(&g_sumexp[rowBase + tid], (double)rowsum[tid]);
    }
}

// ---------------------------------------------------------------------------
// Kernel 2: per token — exact fp32 target logits + cosine.  NO atomics:
// writes per-token values; reduced by final_scalar_kernel.
// tokvals[t] = {nll2, nll3, cos, valid}
// ---------------------------------------------------------------------------
__global__ __launch_bounds__(256)
void finalize_tokens_kernel(const float* __restrict__ p2,
                            const float* __restrict__ p3,
                            const float* __restrict__ W,
                            const int*   __restrict__ targets,
                            const double* __restrict__ g_sumexp,
                            double* __restrict__ tokvals)
{
    const int t   = blockIdx.x;
    const int tid = threadIdx.x;
    const int tg  = targets[t];
    const bool valid = (tg >= 0);
    const float* w = W + (size_t)(valid ? tg : 0) * KDIM;
    const float* a = p2 + (size_t)t * KDIM;
    const float* b = p3 + (size_t)t * KDIM;

    float s22 = 0.f, s33 = 0.f, s23 = 0.f, s2w = 0.f, s3w = 0.f;
    for (int i = tid; i < KDIM; i += 256) {
        float x = a[i], y = b[i], ww = w[i];
        s22 = fmaf(x, x, s22);
        s33 = fmaf(y, y, s33);
        s23 = fmaf(x, y, s23);
        s2w = fmaf(x, ww, s2w);
        s3w = fmaf(y, ww, s3w);
    }
#pragma unroll
    for (int off = 32; off > 0; off >>= 1) {
        s22 += __shfl_down(s22, off);
        s33 += __shfl_down(s33, off);
        s23 += __shfl_down(s23, off);
        s2w += __shfl_down(s2w, off);
        s3w += __shfl_down(s3w, off);
    }
    __shared__ float sm[5][4];
    const int wv = tid >> 6, lane = tid & 63;
    if (lane == 0) {
        sm[0][wv] = s22; sm[1][wv] = s33; sm[2][wv] = s23;
        sm[3][wv] = s2w; sm[4][wv] = s3w;
    }
    __syncthreads();
    if (tid == 0) {
        float S22 = sm[0][0] + sm[0][1] + sm[0][2] + sm[0][3];
        float S33 = sm[1][0] + sm[1][1] + sm[1][2] + sm[1][3];
        float S23 = sm[2][0] + sm[2][1] + sm[2][2] + sm[2][3];
        float S2w = sm[3][0] + sm[3][1] + sm[3][2] + sm[3][3];
        float S3w = sm[4][0] + sm[4][1] + sm[4][2] + sm[4][3];

        float n2 = fmaxf(sqrtf(S22), EPS_COS);
        float n3 = fmaxf(sqrtf(S33), EPS_COS);

        double4 out;
        out.x = valid ? (log(g_sumexp[t])      - (double)S2w) : 0.0;
        out.y = valid ? (log(g_sumexp[BT + t]) - (double)S3w) : 0.0;
        out.z = (double)(S23 / (n2 * n3));
        out.w = valid ? 1.0 : 0.0;
        *(double4*)(tokvals + 4 * (size_t)t) = out;
    }
}

// ---------------------------------------------------------------------------
// Kernel 3: reduce tokvals -> output scalar (one 1024-thread block).
// ---------------------------------------------------------------------------
__global__ __launch_bounds__(1024)
void final_scalar_kernel(const double* __restrict__ tokvals,
                         float* __restrict__ out)
{
    const int tid = threadIdx.x;
    double s0 = 0.0, s1 = 0.0, s2 = 0.0, s3 = 0.0;
    for (int t = tid; t < BT; t += 1024) {
        double4 v = *(const double4*)(tokvals + 4 * (size_t)t);
        s0 += v.x; s1 += v.y; s2 += v.z; s3 += v.w;
    }
#pragma unroll
    for (int off = 32; off > 0; off >>= 1) {
        s0 += __shfl_down(s0, off);
        s1 += __shfl_down(s1, off);
        s2 += __shfl_down(s2, off);
        s3 += __shfl_down(s3, off);
    }
    __shared__ double sm[4][16];
    const int wv = tid >> 6, lane = tid & 63;
    if (lane == 0) { sm[0][wv] = s0; sm[1][wv] = s1; sm[2][wv] = s2; sm[3][wv] = s3; }
    __syncthreads();
    if (tid == 0) {
        double S0 = 0, S1 = 0, S2 = 0, S3 = 0;
#pragma unroll
        for (int i = 0; i < 16; ++i) { S0 += sm[0][i]; S1 += sm[1][i]; S2 += sm[2][i]; S3 += sm[3][i]; }
        double cnt = (S3 > 0.0) ? S3 : 1.0;
        double loss_p2 = S0 / cnt;
        double loss_p3 = S1 / cnt;
        double reward_loss = -REWARD_SCALE * (loss_p2 - loss_p3);
        double divergence  =  DIV_WEIGHT * (S2 / (double)BT);
        out[0] = (float)(reward_loss + divergence);
    }
}

// ---------------------------------------------------------------------------
extern "C" void kernel_launch(void* const* d_in, const int* in_sizes, int n_in,
                              void* d_out, int out_size, void* d_ws, size_t ws_size,
                              hipStream_t stream)
{
    const float* p2  = (const float*)d_in[0];   // [2,2048,768] fp32
    const float* p3  = (const float*)d_in[1];   // [2,2048,768] fp32
    const float* W   = (const float*)d_in[2];   // [50257,768] fp32
    const int*   tgt = (const int*)d_in[3];     // [2,2048]

    double* g_sumexp = (double*)d_ws;                    // 8192 doubles (64 KB)
    double* tokvals  = g_sumexp + M_TOT;                 // 16384 doubles (128 KB)
    char*   fragbase = (char*)d_ws + 196608;

    hipMemsetAsync(d_ws, 0, 65536, stream);   // g_sumexp only

    const size_t need = 196608 + A8_BYTES + W8_BYTES;    // ~45 MB
    if (ws_size >= need) {
        unsigned char* A8 = (unsigned char*)fragbase;
        unsigned char* W8 = A8 + A8_BYTES;

        convert_A8_kernel<<<dim3(64, 12), dim3(256), 0, stream>>>(p2, p3, A8);
        convert_W8_kernel<<<dim3(NBLK, 12), dim3(256), 0, stream>>>(W, W8);
        // grid.x = mb fast: consecutive blocks share nb (B panel L2-hot)
        // and span mb (A slices small, L2-resident everywhere).
        gemm_fp8_kernel<<<dim3(64, NBLK), dim3(256), 0, stream>>>(A8, W8, g_sumexp);
    } else {
        logits_expsum_kernel<<<dim3(NBLK, 64), dim3(256), 0, stream>>>(p2, p3, W, g_sumexp);
    }

    finalize_tokens_kernel<<<dim3(BT), dim3(256), 0, stream>>>(
        p2, p3, W, tgt, g_sumexp, tokvals);

    final_scalar_kernel<<<dim3(1), dim3(1024), 0, stream>>>(tokvals, (float*)d_out);
}

// Round 5
// 1656.872 us; speedup vs baseline: 2.1211x; 2.0606x over previous
//
#include <hip/hip_runtime.h>
#include <math.h>

// Problem constants
#define BT     4096      // B*T tokens per pass
#define M_TOT  8192      // 2 passes stacked
#define VDIM   50257
#define KDIM   768
#define NBLK   393       // ceil(VDIM/128)
#define KC8    6         // 768 / 128 K-chunks (fp8 path)
#define REWARD_SCALE 0.5
#define DIV_WEIGHT   0.1
#define EPS_COS      1e-8f
#define LOG2E        1.44269504088896340736f

typedef float f32x4 __attribute__((ext_vector_type(4)));
typedef int   i32x4v __attribute__((ext_vector_type(4)));
typedef int   i32x8v __attribute__((ext_vector_type(8)));
// register-only concat of two 16B halves into one 32B MFMA operand
#define CAT8(lo_, hi_) __builtin_shufflevector((lo_), (hi_), 0, 1, 2, 3, 4, 5, 6, 7)

// fp8 fragment storage: unit = (128-row blk, k0 of 128, tile of 16 rows)
//   = 2 KB: [h(0,1)][lane(64)][16B], lane -> row = tile*16 + (lane&15),
//   k = (lane>>4)*32 + h*16 + j   (j = byte 0..15)
#define A8_BYTES ((size_t)64 * KC8 * 8 * 2048)    //  6.29 MB
#define W8_BYTES ((size_t)NBLK * KC8 * 8 * 2048)  // 38.6 MB

// ---------------------------------------------------------------------------
// async global->LDS, 16B per lane (wave-uniform base + lane*16 semantics)
// ---------------------------------------------------------------------------
__device__ __forceinline__ void g2l16(const void* g, void* l) {
    __builtin_amdgcn_global_load_lds(
        (const __attribute__((address_space(1))) unsigned int*)g,
        (__attribute__((address_space(3))) unsigned int*)l,
        16, 0, 0);
}

// ---------------------------------------------------------------------------
// Converters: fp32 -> fp8 e4m3 (OCP), pre-swizzled into MFMA fragment order.
// W additionally scaled by log2(e) so GEMM logits come out base-2.
// Each block handles 128 rows x 64 K-cols (half of a K=128 chunk).
// ---------------------------------------------------------------------------
__global__ __launch_bounds__(256)
void convert_A8_kernel(const float* __restrict__ p2, const float* __restrict__ p3,
                       unsigned char* __restrict__ A8)
{
    __shared__ float Ls[128][65];
    const int mb = blockIdx.x;             // 0..63
    const int kc = blockIdx.y;             // 0..11 (64-col half-chunks)
    const int tid = threadIdx.x;
    const int colBase = kc * 64;

#pragma unroll
    for (int p = 0; p < 8; ++p) {
        int i = p * 1024 + tid * 4;
        int r = i >> 6;
        int c = i & 63;
        int m = mb * 128 + r;
        const float* src = (m < BT) ? (p2 + (size_t)m * KDIM)
                                    : (p3 + (size_t)(m - BT) * KDIM);
        float4 v = *(const float4*)(src + colBase + c);
        Ls[r][c + 0] = v.x; Ls[r][c + 1] = v.y;
        Ls[r][c + 2] = v.z; Ls[r][c + 3] = v.w;
    }
    __syncthreads();

    const int k0 = kc >> 1;
    const int gBase = (kc & 1) * 2;        // lane-group base (0 or 2)
#pragma unroll
    for (int p = 0; p < 2; ++p) {
        int f    = tid + p * 256;          // 0..511
        int tile = f >> 6;
        int r6   = f & 63;
        int lp   = r6 >> 1;                // 0..31
        int h    = r6 & 1;
        int lane = gBase * 16 + lp;        // output lane 0..63
        int row  = tile * 16 + (lp & 15);
        int cloc = (lp >> 4) * 32 + h * 16;
        unsigned int d[4];
#pragma unroll
        for (int q = 0; q < 4; ++q) {
            int dd = 0;
            dd = __builtin_amdgcn_cvt_pk_fp8_f32(Ls[row][cloc + q*4 + 0],
                                                 Ls[row][cloc + q*4 + 1], dd, false);
            dd = __builtin_amdgcn_cvt_pk_fp8_f32(Ls[row][cloc + q*4 + 2],
                                                 Ls[row][cloc + q*4 + 3], dd, true);
            d[q] = (unsigned int)dd;
        }
        size_t off = ((size_t)(mb * KC8 + k0) * 8 + tile) * 2048
                   + (size_t)h * 1024 + (size_t)lane * 16;
        *(uint4*)(A8 + off) = make_uint4(d[0], d[1], d[2], d[3]);
    }
}

__global__ __launch_bounds__(256)
void convert_W8_kernel(const float* __restrict__ W, unsigned char* __restrict__ W8)
{
    __shared__ float Ls[128][65];
    const int nb = blockIdx.x;             // 0..392
    const int kc = blockIdx.y;             // 0..11
    const int tid = threadIdx.x;
    const int colBase = kc * 64;

#pragma unroll
    for (int p = 0; p < 8; ++p) {
        int i = p * 1024 + tid * 4;
        int r = i >> 6;
        int c = i & 63;
        int v = nb * 128 + r;
        float4 val = make_float4(0.f, 0.f, 0.f, 0.f);
        if (v < VDIM) val = *(const float4*)(W + (size_t)v * KDIM + colBase + c);
        Ls[r][c + 0] = val.x * LOG2E; Ls[r][c + 1] = val.y * LOG2E;
        Ls[r][c + 2] = val.z * LOG2E; Ls[r][c + 3] = val.w * LOG2E;
    }
    __syncthreads();

    const int k0 = kc >> 1;
    const int gBase = (kc & 1) * 2;
#pragma unroll
    for (int p = 0; p < 2; ++p) {
        int f    = tid + p * 256;
        int tile = f >> 6;
        int r6   = f & 63;
        int lp   = r6 >> 1;
        int h    = r6 & 1;
        int lane = gBase * 16 + lp;
        int row  = tile * 16 + (lp & 15);
        int cloc = (lp >> 4) * 32 + h * 16;
        unsigned int d[4];
#pragma unroll
        for (int q = 0; q < 4; ++q) {
            int dd = 0;
            dd = __builtin_amdgcn_cvt_pk_fp8_f32(Ls[row][cloc + q*4 + 0],
                                                 Ls[row][cloc + q*4 + 1], dd, false);
            dd = __builtin_amdgcn_cvt_pk_fp8_f32(Ls[row][cloc + q*4 + 2],
                                                 Ls[row][cloc + q*4 + 3], dd, true);
            d[q] = (unsigned int)dd;
        }
        size_t off = ((size_t)(nb * KC8 + k0) * 8 + tile) * 2048
                   + (size_t)h * 1024 + (size_t)lane * 16;
        *(uint4*)(W8 + off) = make_uint4(d[0], d[1], d[2], d[3]);
    }
}

// ---------------------------------------------------------------------------
// Main GEMM (fp8 MX, scales = 1.0): 128x128 tile, 256 threads (4 waves 2x2),
// wave tile 64x64, K-chunks of 128 via mfma_scale_f32_16x16x128_f8f6f4.
// Same verified structure/pipe-split as the 681us f16 baseline:
//   A: global_load_lds double-buffered (32 KB LDS), per-k0 __syncthreads.
//   B: direct global->VGPR, single-buffered halves (bl/bh: 32 VGPR),
//      next-k0 prefetch issued after last use, drained by the barrier.
// R4 post-mortem: __launch_bounds__(256,4) capped unified VGPR+AGPR at
// 128/wave; demand is ~150 (acc 64 AGPR + B 32 + A 16 + addr ~20+) ->
// allocator spilled the B fragments every k0 (6.5 GB scratch writes,
// MfmaUtil 4%).  Fix: (256,2) -> 256-reg budget, 2 blocks/CU, no spill.
// ---------------------------------------------------------------------------
__global__ __launch_bounds__(256, 2)
void gemm_fp8_kernel(const unsigned char* __restrict__ A8,
                     const unsigned char* __restrict__ W8,
                     double* __restrict__ g_sumexp)
{
    __shared__ __align__(16) unsigned char As[2][16384];   // 32 KB
    __shared__ float rowsum[128];

    const int tid  = threadIdx.x;
    const int lane = tid & 63;
    const int w    = tid >> 6;       // 0..3
    const int wm   = w >> 1;         // 0..1
    const int wn   = w & 1;          // 0..1
    const int mb   = blockIdx.x;     // 0..63
    const int nb   = blockIdx.y;     // 0..392

    if (tid < 128) rowsum[tid] = 0.0f;

    f32x4 acc[4][4];
#pragma unroll
    for (int i = 0; i < 4; ++i)
#pragma unroll
        for (int j = 0; j < 4; ++j) acc[i][j] = (f32x4)0.0f;

    const unsigned char* Agl = A8 + (size_t)mb * KC8 * 8 * 2048 + (size_t)lane * 16;
    const unsigned char* Bgl = W8 + ((size_t)nb * KC8 * 8 + (size_t)wn * 4) * 2048
                                  + (size_t)lane * 16;
    unsigned char* sDst = &As[0][0] + (size_t)(2 * w) * 2048 + (size_t)lane * 16;
    const unsigned char* aRd = &As[0][0] + (size_t)(wm * 4) * 2048 + (size_t)lane * 16;

    // wave w stages fragment-units {2w, 2w+1} (4 x g2l16 per wave per k0)
#define STAGE8(k0_, buf_)                                                     \
    {                                                                         \
        _Pragma("unroll")                                                     \
        for (int uu = 0; uu < 2; ++uu)                                        \
            _Pragma("unroll")                                                 \
            for (int hh = 0; hh < 2; ++hh)                                    \
                g2l16(Agl + ((size_t)(k0_) * 8 + 2 * w + uu) * 2048           \
                          + (size_t)hh * 1024,                                \
                      sDst + (size_t)(buf_) * 16384 + (size_t)uu * 2048       \
                           + (size_t)hh * 1024);                              \
    }

    i32x4v bl[4], bh[4];                  // B halves, register-resident
#define LOADB(k0_)                                                            \
    {                                                                         \
        _Pragma("unroll")                                                     \
        for (int nt = 0; nt < 4; ++nt) {                                      \
            bl[nt] = *(const i32x4v*)(Bgl + ((size_t)(k0_) * 8 + nt) * 2048); \
            bh[nt] = *(const i32x4v*)(Bgl + ((size_t)(k0_) * 8 + nt) * 2048   \
                                          + 1024);                            \
        }                                                                     \
    }

    STAGE8(0, 0);
    LOADB(0);

#pragma unroll
    for (int k0 = 0; k0 < KC8; ++k0) {
        const int buf = k0 & 1;
        __syncthreads();                       // As[buf] + b[] resident
        if (k0 + 1 < KC8) STAGE8(k0 + 1, buf ^ 1);
#pragma unroll
        for (int tm = 0; tm < 4; ++tm) {
            i32x4v al = *(const i32x4v*)(aRd + (size_t)buf * 16384
                                             + (size_t)tm * 2048);
            i32x4v ah = *(const i32x4v*)(aRd + (size_t)buf * 16384
                                             + (size_t)tm * 2048 + 1024);
            i32x8v a8 = CAT8(al, ah);
#pragma unroll
            for (int nt = 0; nt < 4; ++nt)
                acc[tm][nt] = __builtin_amdgcn_mfma_scale_f32_16x16x128_f8f6f4(
                    a8, CAT8(bl[nt], bh[nt]), acc[tm][nt],
                    0 /*cbsz: A=fp8 e4m3*/, 0 /*blgp: B=fp8 e4m3*/,
                    0, 0x7F7F7F7F /*scale_a = 1.0*/,
                    0, 0x7F7F7F7F /*scale_b = 1.0*/);
        }
        if (k0 + 1 < KC8) LOADB(k0 + 1);       // prefetch next B after last use
    }
#undef STAGE8
#undef LOADB

    // --- epilogue: exp2 (logits pre-scaled by log2e), per-row reduce ---
    __syncthreads();
    const int colBase = nb * 128 + wn * 64;
    const int quad = lane >> 4;
    const int cidx = lane & 15;
#pragma unroll
    for (int tm = 0; tm < 4; ++tm) {
#pragma unroll
        for (int r = 0; r < 4; ++r) {
            float s = 0.0f;
#pragma unroll
            for (int tn = 0; tn < 4; ++tn) {
                int col = colBase + tn * 16 + cidx;
                if (col < VDIM) s += __builtin_amdgcn_exp2f(acc[tm][tn][r]);
            }
            s += __shfl_xor(s, 1);
            s += __shfl_xor(s, 2);
            s += __shfl_xor(s, 4);
            s += __shfl_xor(s, 8);
            if (cidx == 0) {
                int row = wm * 64 + tm * 16 + quad * 4 + r;
                atomicAdd(&rowsum[row], s);
            }
        }
    }
    __syncthreads();
    if (tid < 128) {
        atomicAdd(&g_sumexp[(size_t)mb * 128 + tid], (double)rowsum[tid]);
    }
}

// ---------------------------------------------------------------------------
// Fallback fp32 GEMM (round-2 kernel) if workspace is too small.
// ---------------------------------------------------------------------------
#define BM 128
#define BN 128
#define BK 16
#define LDPAD 4
__global__ __launch_bounds__(256)
void logits_expsum_kernel(const float* __restrict__ p2,
                          const float* __restrict__ p3,
                          const float* __restrict__ W,
                          double* __restrict__ g_sumexp)
{
    __shared__ float As[BK][BM + LDPAD];
    __shared__ float Bsh[BK][BN + LDPAD];
    __shared__ float rowsum[BM];

    const int tid     = threadIdx.x;
    const int rowBase = blockIdx.y * BM;
    const int colBase = blockIdx.x * BN;

    if (tid < BM) rowsum[tid] = 0.0f;

    float acc[8][8];
#pragma unroll
    for (int i = 0; i < 8; ++i)
#pragma unroll
        for (int j = 0; j < 8; ++j) acc[i][j] = 0.0f;

    const int ty = tid >> 4;
    const int tx = tid & 15;
    const int r0 = ty * 8;
    const int c0 = tx * 4;

    for (int k0 = 0; k0 < KDIM; k0 += BK) {
        __syncthreads();
#pragma unroll
        for (int l = 0; l < 2; ++l) {
            int id  = tid + l * 256;
            int row = id >> 2;
            int kq  = id & 3;
            int m   = rowBase + row;
            const float* src = (m < BT) ? (p2 + (size_t)m * KDIM)
                                        : (p3 + (size_t)(m - BT) * KDIM);
            float4 v = *(const float4*)(src + k0 + kq * 4);
            As[kq * 4 + 0][row] = v.x;
            As[kq * 4 + 1][row] = v.y;
            As[kq * 4 + 2][row] = v.z;
            As[kq * 4 + 3][row] = v.w;
        }
#pragma unroll
        for (int l = 0; l < 2; ++l) {
            int id  = tid + l * 256;
            int row = id >> 2;
            int kq  = id & 3;
            int c   = colBase + row;
            int cs  = (c < VDIM) ? c : (VDIM - 1);
            float4 v = *(const float4*)(W + (size_t)cs * KDIM + k0 + kq * 4);
            Bsh[kq * 4 + 0][row] = v.x;
            Bsh[kq * 4 + 1][row] = v.y;
            Bsh[kq * 4 + 2][row] = v.z;
            Bsh[kq * 4 + 3][row] = v.w;
        }
        __syncthreads();
#pragma unroll
        for (int kk = 0; kk < BK; ++kk) {
            float a[8], bb[8];
            *(float4*)&a[0]  = *(const float4*)&As[kk][r0];
            *(float4*)&a[4]  = *(const float4*)&As[kk][r0 + 4];
            *(float4*)&bb[0] = *(const float4*)&Bsh[kk][c0];
            *(float4*)&bb[4] = *(const float4*)&Bsh[kk][64 + c0];
#pragma unroll
            for (int i = 0; i < 8; ++i)
#pragma unroll
                for (int j = 0; j < 8; ++j)
                    acc[i][j] = fmaf(a[i], bb[j], acc[i][j]);
        }
    }

    __syncthreads();
#pragma unroll
    for (int i = 0; i < 8; ++i) {
        float s = 0.0f;
#pragma unroll
        for (int j = 0; j < 8; ++j) {
            int c = colBase + ((j < 4) ? (c0 + j) : (64 + c0 + (j - 4)));
            if (c < VDIM) s += expf(acc[i][j]);
        }
        atomicAdd(&rowsum[r0 + i], s);
    }
    __syncthreads();
    if (tid < BM) {
        atomicAdd(&g_sumexp[rowBase + tid], (double)rowsum[tid]);
    }
}

// ---------------------------------------------------------------------------
// Kernel 2: per token — exact fp32 target logits + cosine.  NO atomics:
// writes per-token values; reduced by final_scalar_kernel.
// tokvals[t] = {nll2, nll3, cos, valid}
// ---------------------------------------------------------------------------
__global__ __launch_bounds__(256)
void finalize_tokens_kernel(const float* __restrict__ p2,
                            const float* __restrict__ p3,
                            const float* __restrict__ W,
                            const int*   __restrict__ targets,
                            const double* __restrict__ g_sumexp,
                            double* __restrict__ tokvals)
{
    const int t   = blockIdx.x;
    const int tid = threadIdx.x;
    const int tg  = targets[t];
    const bool valid = (tg >= 0);
    const float* w = W + (size_t)(valid ? tg : 0) * KDIM;
    const float* a = p2 + (size_t)t * KDIM;
    const float* b = p3 + (size_t)t * KDIM;

    float s22 = 0.f, s33 = 0.f, s23 = 0.f, s2w = 0.f, s3w = 0.f;
    for (int i = tid; i < KDIM; i += 256) {
        float x = a[i], y = b[i], ww = w[i];
        s22 = fmaf(x, x, s22);
        s33 = fmaf(y, y, s33);
        s23 = fmaf(x, y, s23);
        s2w = fmaf(x, ww, s2w);
        s3w = fmaf(y, ww, s3w);
    }
#pragma unroll
    for (int off = 32; off > 0; off >>= 1) {
        s22 += __shfl_down(s22, off);
        s33 += __shfl_down(s33, off);
        s23 += __shfl_down(s23, off);
        s2w += __shfl_down(s2w, off);
        s3w += __shfl_down(s3w, off);
    }
    __shared__ float sm[5][4];
    const int wv = tid >> 6, lane = tid & 63;
    if (lane == 0) {
        sm[0][wv] = s22; sm[1][wv] = s33; sm[2][wv] = s23;
        sm[3][wv] = s2w; sm[4][wv] = s3w;
    }
    __syncthreads();
    if (tid == 0) {
        float S22 = sm[0][0] + sm[0][1] + sm[0][2] + sm[0][3];
        float S33 = sm[1][0] + sm[1][1] + sm[1][2] + sm[1][3];
        float S23 = sm[2][0] + sm[2][1] + sm[2][2] + sm[2][3];
        float S2w = sm[3][0] + sm[3][1] + sm[3][2] + sm[3][3];
        float S3w = sm[4][0] + sm[4][1] + sm[4][2] + sm[4][3];

        float n2 = fmaxf(sqrtf(S22), EPS_COS);
        float n3 = fmaxf(sqrtf(S33), EPS_COS);

        double4 out;
        out.x = valid ? (log(g_sumexp[t])      - (double)S2w) : 0.0;
        out.y = valid ? (log(g_sumexp[BT + t]) - (double)S3w) : 0.0;
        out.z = (double)(S23 / (n2 * n3));
        out.w = valid ? 1.0 : 0.0;
        *(double4*)(tokvals + 4 * (size_t)t) = out;
    }
}

// ---------------------------------------------------------------------------
// Kernel 3: reduce tokvals -> output scalar (one 1024-thread block).
// ---------------------------------------------------------------------------
__global__ __launch_bounds__(1024)
void final_scalar_kernel(const double* __restrict__ tokvals,
                         float* __restrict__ out)
{
    const int tid = threadIdx.x;
    double s0 = 0.0, s1 = 0.0, s2 = 0.0, s3 = 0.0;
    for (int t = tid; t < BT; t += 1024) {
        double4 v = *(const double4*)(tokvals + 4 * (size_t)t);
        s0 += v.x; s1 += v.y; s2 += v.z; s3 += v.w;
    }
#pragma unroll
    for (int off = 32; off > 0; off >>= 1) {
        s0 += __shfl_down(s0, off);
        s1 += __shfl_down(s1, off);
        s2 += __shfl_down(s2, off);
        s3 += __shfl_down(s3, off);
    }
    __shared__ double sm[4][16];
    const int wv = tid >> 6, lane = tid & 63;
    if (lane == 0) { sm[0][wv] = s0; sm[1][wv] = s1; sm[2][wv] = s2; sm[3][wv] = s3; }
    __syncthreads();
    if (tid == 0) {
        double S0 = 0, S1 = 0, S2 = 0, S3 = 0;
#pragma unroll
        for (int i = 0; i < 16; ++i) { S0 += sm[0][i]; S1 += sm[1][i]; S2 += sm[2][i]; S3 += sm[3][i]; }
        double cnt = (S3 > 0.0) ? S3 : 1.0;
        double loss_p2 = S0 / cnt;
        double loss_p3 = S1 / cnt;
        double reward_loss = -REWARD_SCALE * (loss_p2 - loss_p3);
        double divergence  =  DIV_WEIGHT * (S2 / (double)BT);
        out[0] = (float)(reward_loss + divergence);
    }
}

// ---------------------------------------------------------------------------
extern "C" void kernel_launch(void* const* d_in, const int* in_sizes, int n_in,
                              void* d_out, int out_size, void* d_ws, size_t ws_size,
                              hipStream_t stream)
{
    const float* p2  = (const float*)d_in[0];   // [2,2048,768] fp32
    const float* p3  = (const float*)d_in[1];   // [2,2048,768] fp32
    const float* W   = (const float*)d_in[2];   // [50257,768] fp32
    const int*   tgt = (const int*)d_in[3];     // [2,2048]

    double* g_sumexp = (double*)d_ws;                    // 8192 doubles (64 KB)
    double* tokvals  = g_sumexp + M_TOT;                 // 16384 doubles (128 KB)
    char*   fragbase = (char*)d_ws + 196608;

    hipMemsetAsync(d_ws, 0, 65536, stream);   // g_sumexp only

    const size_t need = 196608 + A8_BYTES + W8_BYTES;    // ~45 MB
    if (ws_size >= need) {
        unsigned char* A8 = (unsigned char*)fragbase;
        unsigned char* W8 = A8 + A8_BYTES;

        convert_A8_kernel<<<dim3(64, 12), dim3(256), 0, stream>>>(p2, p3, A8);
        convert_W8_kernel<<<dim3(NBLK, 12), dim3(256), 0, stream>>>(W, W8);
        // grid.x = mb fast: consecutive blocks share nb (B panel L2-hot)
        // and span mb (A slices small, L2-resident everywhere).
        gemm_fp8_kernel<<<dim3(64, NBLK), dim3(256), 0, stream>>>(A8, W8, g_sumexp);
    } else {
        logits_expsum_kernel<<<dim3(NBLK, 64), dim3(256), 0, stream>>>(p2, p3, W, g_sumexp);
    }

    finalize_tokens_kernel<<<dim3(BT), dim3(256), 0, stream>>>(
        p2, p3, W, tgt, g_sumexp, tokvals);

    final_scalar_kernel<<<dim3(1), dim3(1024), 0, stream>>>(tokvals, (float*)d_out);
}

// Round 6
// 1569.487 us; speedup vs baseline: 2.2392x; 1.0557x over previous
//
#include <hip/hip_runtime.h>
#include <math.h>

// Problem constants
#define BT     4096      // B*T tokens per pass
#define M_TOT  8192      // 2 passes stacked
#define VDIM   50257
#define KDIM   768
#define NBLK   393       // ceil(VDIM/128)
#define KC8    6         // 768 / 128 K-chunks (fp8 path)
#define REWARD_SCALE 0.5
#define DIV_WEIGHT   0.1
#define EPS_COS      1e-8f
#define LOG2E        1.44269504088896340736f

typedef float f32x4 __attribute__((ext_vector_type(4)));
typedef int   i32x4v __attribute__((ext_vector_type(4)));
typedef int   i32x8v __attribute__((ext_vector_type(8)));
// register-only concat of two 16B halves into one 32B MFMA operand (A only)
#define CAT8(lo_, hi_) __builtin_shufflevector((lo_), (hi_), 0, 1, 2, 3, 4, 5, 6, 7)

// fp8 fragment storage, unit = (16-row tile) x (K=128 chunk) = 2048 B.
//  A8 (LDS-staged via global_load_lds, lane*16 DMA semantics):
//     [h(0,1)][lane(64)][16B] ; lane -> row = tile*16 + (lane&15),
//     k = (lane>>4)*32 + h*16 + j
//  W8 (direct global->VGPR): LANE-CONTIGUOUS 32 B so one i32x8v load fills
//     an aligned 8-reg tuple (no half-merge v_movs -> no spill):
//     [lane(64)][32B] ; byte j of lane's 32 = k = (lane>>4)*32 + j
#define A8_BYTES ((size_t)64 * KC8 * 8 * 2048)    //  6.29 MB
#define W8_BYTES ((size_t)NBLK * KC8 * 8 * 2048)  // 38.6 MB

// ---------------------------------------------------------------------------
// async global->LDS, 16B per lane (wave-uniform base + lane*16 semantics)
// ---------------------------------------------------------------------------
__device__ __forceinline__ void g2l16(const void* g, void* l) {
    __builtin_amdgcn_global_load_lds(
        (const __attribute__((address_space(1))) unsigned int*)g,
        (__attribute__((address_space(3))) unsigned int*)l,
        16, 0, 0);
}

// ---------------------------------------------------------------------------
// Converters: fp32 -> fp8 e4m3 (OCP), pre-swizzled into MFMA fragment order.
// W additionally scaled by log2(e) so GEMM logits come out base-2.
// Each block handles 128 rows x 64 K-cols (half of a K=128 chunk).
// ---------------------------------------------------------------------------
__global__ __launch_bounds__(256)
void convert_A8_kernel(const float* __restrict__ p2, const float* __restrict__ p3,
                       unsigned char* __restrict__ A8)
{
    __shared__ float Ls[128][65];
    const int mb = blockIdx.x;             // 0..63
    const int kc = blockIdx.y;             // 0..11 (64-col half-chunks)
    const int tid = threadIdx.x;
    const int colBase = kc * 64;

#pragma unroll
    for (int p = 0; p < 8; ++p) {
        int i = p * 1024 + tid * 4;
        int r = i >> 6;
        int c = i & 63;
        int m = mb * 128 + r;
        const float* src = (m < BT) ? (p2 + (size_t)m * KDIM)
                                    : (p3 + (size_t)(m - BT) * KDIM);
        float4 v = *(const float4*)(src + colBase + c);
        Ls[r][c + 0] = v.x; Ls[r][c + 1] = v.y;
        Ls[r][c + 2] = v.z; Ls[r][c + 3] = v.w;
    }
    __syncthreads();

    const int k0 = kc >> 1;
    const int gBase = (kc & 1) * 2;        // lane-group base (0 or 2)
#pragma unroll
    for (int p = 0; p < 2; ++p) {
        int f    = tid + p * 256;          // 0..511
        int tile = f >> 6;
        int r6   = f & 63;
        int lp   = r6 >> 1;                // 0..31
        int h    = r6 & 1;
        int lane = gBase * 16 + lp;        // output lane 0..63
        int row  = tile * 16 + (lp & 15);
        int cloc = (lp >> 4) * 32 + h * 16;
        unsigned int d[4];
#pragma unroll
        for (int q = 0; q < 4; ++q) {
            int dd = 0;
            dd = __builtin_amdgcn_cvt_pk_fp8_f32(Ls[row][cloc + q*4 + 0],
                                                 Ls[row][cloc + q*4 + 1], dd, false);
            dd = __builtin_amdgcn_cvt_pk_fp8_f32(Ls[row][cloc + q*4 + 2],
                                                 Ls[row][cloc + q*4 + 3], dd, true);
            d[q] = (unsigned int)dd;
        }
        // A8: [h][lane][16B] within the 2 KB unit (g2l16-compatible)
        size_t off = ((size_t)(mb * KC8 + k0) * 8 + tile) * 2048
                   + (size_t)h * 1024 + (size_t)lane * 16;
        *(uint4*)(A8 + off) = make_uint4(d[0], d[1], d[2], d[3]);
    }
}

__global__ __launch_bounds__(256)
void convert_W8_kernel(const float* __restrict__ W, unsigned char* __restrict__ W8)
{
    __shared__ float Ls[128][65];
    const int nb = blockIdx.x;             // 0..392
    const int kc = blockIdx.y;             // 0..11
    const int tid = threadIdx.x;
    const int colBase = kc * 64;

#pragma unroll
    for (int p = 0; p < 8; ++p) {
        int i = p * 1024 + tid * 4;
        int r = i >> 6;
        int c = i & 63;
        int v = nb * 128 + r;
        float4 val = make_float4(0.f, 0.f, 0.f, 0.f);
        if (v < VDIM) val = *(const float4*)(W + (size_t)v * KDIM + colBase + c);
        Ls[r][c + 0] = val.x * LOG2E; Ls[r][c + 1] = val.y * LOG2E;
        Ls[r][c + 2] = val.z * LOG2E; Ls[r][c + 3] = val.w * LOG2E;
    }
    __syncthreads();

    const int k0 = kc >> 1;
    const int gBase = (kc & 1) * 2;
#pragma unroll
    for (int p = 0; p < 2; ++p) {
        int f    = tid + p * 256;
        int tile = f >> 6;
        int r6   = f & 63;
        int lp   = r6 >> 1;
        int h    = r6 & 1;
        int lane = gBase * 16 + lp;
        int row  = tile * 16 + (lp & 15);
        int cloc = (lp >> 4) * 32 + h * 16;
        unsigned int d[4];
#pragma unroll
        for (int q = 0; q < 4; ++q) {
            int dd = 0;
            dd = __builtin_amdgcn_cvt_pk_fp8_f32(Ls[row][cloc + q*4 + 0],
                                                 Ls[row][cloc + q*4 + 1], dd, false);
            dd = __builtin_amdgcn_cvt_pk_fp8_f32(Ls[row][cloc + q*4 + 2],
                                                 Ls[row][cloc + q*4 + 3], dd, true);
            d[q] = (unsigned int)dd;
        }
        // W8: LANE-CONTIGUOUS [lane][32B] within the 2 KB unit
        size_t off = ((size_t)(nb * KC8 + k0) * 8 + tile) * 2048
                   + (size_t)lane * 32 + (size_t)h * 16;
        *(uint4*)(W8 + off) = make_uint4(d[0], d[1], d[2], d[3]);
    }
}

// ---------------------------------------------------------------------------
// Main GEMM (fp8 MX, scales = 1.0): 128x128 tile, 256 threads (4 waves 2x2),
// wave tile 64x64, K-chunks of 128 via mfma_scale_f32_16x16x128_f8f6f4.
// Pipe split as the 681us f16 baseline: A via global_load_lds dbuf LDS,
// B direct global->VGPR with next-k0 prefetch.
// R5 post-mortem: gfx950 unified-RF quantum is {64,128,256}; acc=64 AGPR
// forces arch cap 128; demand was ~145 (CAT8 half-merges for B kept 4x8
// transient tuples live) -> 18-reg spill/k0 (2.8 GB scratch).  Fix: W8 is
// now lane-contiguous 32 B, so each B fragment is ONE aligned i32x8v load
// (no merges).  Arch demand ~110 <= 128 -> no spill.
// ---------------------------------------------------------------------------
__global__ __launch_bounds__(256, 2)
void gemm_fp8_kernel(const unsigned char* __restrict__ A8,
                     const unsigned char* __restrict__ W8,
                     double* __restrict__ g_sumexp)
{
    __shared__ __align__(16) unsigned char As[2][16384];   // 32 KB
    __shared__ float rowsum[128];

    const int tid  = threadIdx.x;
    const int lane = tid & 63;
    const int w    = tid >> 6;       // 0..3
    const int wm   = w >> 1;         // 0..1
    const int wn   = w & 1;          // 0..1
    const int mb   = blockIdx.x;     // 0..63
    const int nb   = blockIdx.y;     // 0..392

    if (tid < 128) rowsum[tid] = 0.0f;

    f32x4 acc[4][4];
#pragma unroll
    for (int i = 0; i < 4; ++i)
#pragma unroll
        for (int j = 0; j < 4; ++j) acc[i][j] = (f32x4)0.0f;

    const unsigned char* Agl = A8 + (size_t)mb * KC8 * 8 * 2048 + (size_t)lane * 16;
    const unsigned char* Bgl = W8 + ((size_t)nb * KC8 * 8 + (size_t)wn * 4) * 2048
                                  + (size_t)lane * 32;
    unsigned char* sDst = &As[0][0] + (size_t)(2 * w) * 2048 + (size_t)lane * 16;
    const unsigned char* aRd = &As[0][0] + (size_t)(wm * 4) * 2048 + (size_t)lane * 16;

    // wave w stages fragment-units {2w, 2w+1} (4 x g2l16 per wave per k0)
#define STAGE8(k0_, buf_)                                                     \
    {                                                                         \
        _Pragma("unroll")                                                     \
        for (int uu = 0; uu < 2; ++uu)                                        \
            _Pragma("unroll")                                                 \
            for (int hh = 0; hh < 2; ++hh)                                    \
                g2l16(Agl + ((size_t)(k0_) * 8 + 2 * w + uu) * 2048           \
                          + (size_t)hh * 1024,                                \
                      sDst + (size_t)(buf_) * 16384 + (size_t)uu * 2048       \
                           + (size_t)hh * 1024);                              \
    }

    i32x8v b8[4];                         // B fragments, single-load tuples
#define LOADB(k0_)                                                            \
    {                                                                         \
        _Pragma("unroll")                                                     \
        for (int nt = 0; nt < 4; ++nt)                                        \
            b8[nt] = *(const i32x8v*)(Bgl + ((size_t)(k0_) * 8 + nt) * 2048); \
    }

    STAGE8(0, 0);
    LOADB(0);

#pragma unroll
    for (int k0 = 0; k0 < KC8; ++k0) {
        const int buf = k0 & 1;
        __syncthreads();                       // As[buf] + b8[] resident
        if (k0 + 1 < KC8) STAGE8(k0 + 1, buf ^ 1);
#pragma unroll
        for (int tm = 0; tm < 4; ++tm) {
            i32x4v al = *(const i32x4v*)(aRd + (size_t)buf * 16384
                                             + (size_t)tm * 2048);
            i32x4v ah = *(const i32x4v*)(aRd + (size_t)buf * 16384
                                             + (size_t)tm * 2048 + 1024);
            i32x8v a8 = CAT8(al, ah);
#pragma unroll
            for (int nt = 0; nt < 4; ++nt)
                acc[tm][nt] = __builtin_amdgcn_mfma_scale_f32_16x16x128_f8f6f4(
                    a8, b8[nt], acc[tm][nt],
                    0 /*cbsz: A=fp8 e4m3*/, 0 /*blgp: B=fp8 e4m3*/,
                    0, 0x7F7F7F7F /*scale_a = 1.0*/,
                    0, 0x7F7F7F7F /*scale_b = 1.0*/);
        }
        if (k0 + 1 < KC8) LOADB(k0 + 1);       // prefetch next B after last use
    }
#undef STAGE8
#undef LOADB

    // --- epilogue: exp2 (logits pre-scaled by log2e), per-row reduce ---
    __syncthreads();
    const int colBase = nb * 128 + wn * 64;
    const int quad = lane >> 4;
    const int cidx = lane & 15;
#pragma unroll
    for (int tm = 0; tm < 4; ++tm) {
#pragma unroll
        for (int r = 0; r < 4; ++r) {
            float s = 0.0f;
#pragma unroll
            for (int tn = 0; tn < 4; ++tn) {
                int col = colBase + tn * 16 + cidx;
                if (col < VDIM) s += __builtin_amdgcn_exp2f(acc[tm][tn][r]);
            }
            s += __shfl_xor(s, 1);
            s += __shfl_xor(s, 2);
            s += __shfl_xor(s, 4);
            s += __shfl_xor(s, 8);
            if (cidx == 0) {
                int row = wm * 64 + tm * 16 + quad * 4 + r;
                atomicAdd(&rowsum[row], s);
            }
        }
    }
    __syncthreads();
    if (tid < 128) {
        atomicAdd(&g_sumexp[(size_t)mb * 128 + tid], (double)rowsum[tid]);
    }
}

// ---------------------------------------------------------------------------
// Fallback fp32 GEMM (round-2 kernel) if workspace is too small.
// ---------------------------------------------------------------------------
#define BM 128
#define BN 128
#define BK 16
#define LDPAD 4
__global__ __launch_bounds__(256)
void logits_expsum_kernel(const float* __restrict__ p2,
                          const float* __restrict__ p3,
                          const float* __restrict__ W,
                          double* __restrict__ g_sumexp)
{
    __shared__ float As[BK][BM + LDPAD];
    __shared__ float Bsh[BK][BN + LDPAD];
    __shared__ float rowsum[BM];

    const int tid     = threadIdx.x;
    const int rowBase = blockIdx.y * BM;
    const int colBase = blockIdx.x * BN;

    if (tid < BM) rowsum[tid] = 0.0f;

    float acc[8][8];
#pragma unroll
    for (int i = 0; i < 8; ++i)
#pragma unroll
        for (int j = 0; j < 8; ++j) acc[i][j] = 0.0f;

    const int ty = tid >> 4;
    const int tx = tid & 15;
    const int r0 = ty * 8;
    const int c0 = tx * 4;

    for (int k0 = 0; k0 < KDIM; k0 += BK) {
        __syncthreads();
#pragma unroll
        for (int l = 0; l < 2; ++l) {
            int id  = tid + l * 256;
            int row = id >> 2;
            int kq  = id & 3;
            int m   = rowBase + row;
            const float* src = (m < BT) ? (p2 + (size_t)m * KDIM)
                                        : (p3 + (size_t)(m - BT) * KDIM);
            float4 v = *(const float4*)(src + k0 + kq * 4);
            As[kq * 4 + 0][row] = v.x;
            As[kq * 4 + 1][row] = v.y;
            As[kq * 4 + 2][row] = v.z;
            As[kq * 4 + 3][row] = v.w;
        }
#pragma unroll
        for (int l = 0; l < 2; ++l) {
            int id  = tid + l * 256;
            int row = id >> 2;
            int kq  = id & 3;
            int c   = colBase + row;
            int cs  = (c < VDIM) ? c : (VDIM - 1);
            float4 v = *(const float4*)(W + (size_t)cs * KDIM + k0 + kq * 4);
            Bsh[kq * 4 + 0][row] = v.x;
            Bsh[kq * 4 + 1][row] = v.y;
            Bsh[kq * 4 + 2][row] = v.z;
            Bsh[kq * 4 + 3][row] = v.w;
        }
        __syncthreads();
#pragma unroll
        for (int kk = 0; kk < BK; ++kk) {
            float a[8], bb[8];
            *(float4*)&a[0]  = *(const float4*)&As[kk][r0];
            *(float4*)&a[4]  = *(const float4*)&As[kk][r0 + 4];
            *(float4*)&bb[0] = *(const float4*)&Bsh[kk][c0];
            *(float4*)&bb[4] = *(const float4*)&Bsh[kk][64 + c0];
#pragma unroll
            for (int i = 0; i < 8; ++i)
#pragma unroll
                for (int j = 0; j < 8; ++j)
                    acc[i][j] = fmaf(a[i], bb[j], acc[i][j]);
        }
    }

    __syncthreads();
#pragma unroll
    for (int i = 0; i < 8; ++i) {
        float s = 0.0f;
#pragma unroll
        for (int j = 0; j < 8; ++j) {
            int c = colBase + ((j < 4) ? (c0 + j) : (64 + c0 + (j - 4)));
            if (c < VDIM) s += expf(acc[i][j]);
        }
        atomicAdd(&rowsum[r0 + i], s);
    }
    __syncthreads();
    if (tid < BM) {
        atomicAdd(&g_sumexp[rowBase + tid], (double)rowsum[tid]);
    }
}

// ---------------------------------------------------------------------------
// Kernel 2: per token — exact fp32 target logits + cosine.  NO atomics:
// writes per-token values; reduced by final_scalar_kernel.
// tokvals[t] = {nll2, nll3, cos, valid}
// ---------------------------------------------------------------------------
__global__ __launch_bounds__(256)
void finalize_tokens_kernel(const float* __restrict__ p2,
                            const float* __restrict__ p3,
                            const float* __restrict__ W,
                            const int*   __restrict__ targets,
                            const double* __restrict__ g_sumexp,
                            double* __restrict__ tokvals)
{
    const int t   = blockIdx.x;
    const int tid = threadIdx.x;
    const int tg  = targets[t];
    const bool valid = (tg >= 0);
    const float* w = W + (size_t)(valid ? tg : 0) * KDIM;
    const float* a = p2 + (size_t)t * KDIM;
    const float* b = p3 + (size_t)t * KDIM;

    float s22 = 0.f, s33 = 0.f, s23 = 0.f, s2w = 0.f, s3w = 0.f;
    for (int i = tid; i < KDIM; i += 256) {
        float x = a[i], y = b[i], ww = w[i];
        s22 = fmaf(x, x, s22);
        s33 = fmaf(y, y, s33);
        s23 = fmaf(x, y, s23);
        s2w = fmaf(x, ww, s2w);
        s3w = fmaf(y, ww, s3w);
    }
#pragma unroll
    for (int off = 32; off > 0; off >>= 1) {
        s22 += __shfl_down(s22, off);
        s33 += __shfl_down(s33, off);
        s23 += __shfl_down(s23, off);
        s2w += __shfl_down(s2w, off);
        s3w += __shfl_down(s3w, off);
    }
    __shared__ float sm[5][4];
    const int wv = tid >> 6, lane = tid & 63;
    if (lane == 0) {
        sm[0][wv] = s22; sm[1][wv] = s33; sm[2][wv] = s23;
        sm[3][wv] = s2w; sm[4][wv] = s3w;
    }
    __syncthreads();
    if (tid == 0) {
        float S22 = sm[0][0] + sm[0][1] + sm[0][2] + sm[0][3];
        float S33 = sm[1][0] + sm[1][1] + sm[1][2] + sm[1][3];
        float S23 = sm[2][0] + sm[2][1] + sm[2][2] + sm[2][3];
        float S2w = sm[3][0] + sm[3][1] + sm[3][2] + sm[3][3];
        float S3w = sm[4][0] + sm[4][1] + sm[4][2] + sm[4][3];

        float n2 = fmaxf(sqrtf(S22), EPS_COS);
        float n3 = fmaxf(sqrtf(S33), EPS_COS);

        double4 out;
        out.x = valid ? (log(g_sumexp[t])      - (double)S2w) : 0.0;
        out.y = valid ? (log(g_sumexp[BT + t]) - (double)S3w) : 0.0;
        out.z = (double)(S23 / (n2 * n3));
        out.w = valid ? 1.0 : 0.0;
        *(double4*)(tokvals + 4 * (size_t)t) = out;
    }
}

// ---------------------------------------------------------------------------
// Kernel 3: reduce tokvals -> output scalar (one 1024-thread block).
// ---------------------------------------------------------------------------
__global__ __launch_bounds__(1024)
void final_scalar_kernel(const double* __restrict__ tokvals,
                         float* __restrict__ out)
{
    const int tid = threadIdx.x;
    double s0 = 0.0, s1 = 0.0, s2 = 0.0, s3 = 0.0;
    for (int t = tid; t < BT; t += 1024) {
        double4 v = *(const double4*)(tokvals + 4 * (size_t)t);
        s0 += v.x; s1 += v.y; s2 += v.z; s3 += v.w;
    }
#pragma unroll
    for (int off = 32; off > 0; off >>= 1) {
        s0 += __shfl_down(s0, off);
        s1 += __shfl_down(s1, off);
        s2 += __shfl_down(s2, off);
        s3 += __shfl_down(s3, off);
    }
    __shared__ double sm[4][16];
    const int wv = tid >> 6, lane = tid & 63;
    if (lane == 0) { sm[0][wv] = s0; sm[1][wv] = s1; sm[2][wv] = s2; sm[3][wv] = s3; }
    __syncthreads();
    if (tid == 0) {
        double S0 = 0, S1 = 0, S2 = 0, S3 = 0;
#pragma unroll
        for (int i = 0; i < 16; ++i) { S0 += sm[0][i]; S1 += sm[1][i]; S2 += sm[2][i]; S3 += sm[3][i]; }
        double cnt = (S3 > 0.0) ? S3 : 1.0;
        double loss_p2 = S0 / cnt;
        double loss_p3 = S1 / cnt;
        double reward_loss = -REWARD_SCALE * (loss_p2 - loss_p3);
        double divergence  =  DIV_WEIGHT * (S2 / (double)BT);
        out[0] = (float)(reward_loss + divergence);
    }
}

// ---------------------------------------------------------------------------
extern "C" void kernel_launch(void* const* d_in, const int* in_sizes, int n_in,
                              void* d_out, int out_size, void* d_ws, size_t ws_size,
                              hipStream_t stream)
{
    const float* p2  = (const float*)d_in[0];   // [2,2048,768] fp32
    const float* p3  = (const float*)d_in[1];   // [2,2048,768] fp32
    const float* W   = (const float*)d_in[2];   // [50257,768] fp32
    const int*   tgt = (const int*)d_in[3];     // [2,2048]

    double* g_sumexp = (double*)d_ws;                    // 8192 doubles (64 KB)
    double* tokvals  = g_sumexp + M_TOT;                 // 16384 doubles (128 KB)
    char*   fragbase = (char*)d_ws + 196608;

    hipMemsetAsync(d_ws, 0, 65536, stream);   // g_sumexp only

    const size_t need = 196608 + A8_BYTES + W8_BYTES;    // ~45 MB
    if (ws_size >= need) {
        unsigned char* A8 = (unsigned char*)fragbase;
        unsigned char* W8 = A8 + A8_BYTES;

        convert_A8_kernel<<<dim3(64, 12), dim3(256), 0, stream>>>(p2, p3, A8);
        convert_W8_kernel<<<dim3(NBLK, 12), dim3(256), 0, stream>>>(W, W8);
        // grid.x = mb fast: consecutive blocks share nb (B panel L2-hot)
        // and span mb (A slices small, L2-resident everywhere).
        gemm_fp8_kernel<<<dim3(64, NBLK), dim3(256), 0, stream>>>(A8, W8, g_sumexp);
    } else {
        logits_expsum_kernel<<<dim3(NBLK, 64), dim3(256), 0, stream>>>(p2, p3, W, g_sumexp);
    }

    finalize_tokens_kernel<<<dim3(BT), dim3(256), 0, stream>>>(
        p2, p3, W, tgt, g_sumexp, tokvals);

    final_scalar_kernel<<<dim3(1), dim3(1024), 0, stream>>>(tokvals, (float*)d_out);
}

// Round 7
// 1069.991 us; speedup vs baseline: 3.2845x; 1.4668x over previous
//
#include <hip/hip_runtime.h>
#include <math.h>

// Problem constants
#define BT     4096      // B*T tokens per pass
#define M_TOT  8192      // 2 passes stacked
#define VDIM   50257
#define KDIM   768
#define NBLK   393       // ceil(VDIM/128)
#define KC8    6         // 768 / 128 K-chunks (fp8 path)
#define REWARD_SCALE 0.5
#define DIV_WEIGHT   0.1
#define EPS_COS      1e-8f
#define LOG2E        1.44269504088896340736f

typedef float f32x4 __attribute__((ext_vector_type(4)));
typedef int   i32x4v __attribute__((ext_vector_type(4)));
typedef int   i32x8v __attribute__((ext_vector_type(8)));
// register-only concat of two 16B halves into one 32B MFMA operand (A only)
#define CAT8(lo_, hi_) __builtin_shufflevector((lo_), (hi_), 0, 1, 2, 3, 4, 5, 6, 7)

// fp8 fragment storage, unit = (16-row tile) x (K=128 chunk) = 2048 B.
//  A8 (LDS-staged via global_load_lds, lane*16 DMA semantics):
//     [h(0,1)][lane(64)][16B] ; lane -> row = tile*16 + (lane&15),
//     k = (lane>>4)*32 + h*16 + j
//  W8 (direct global->VGPR): LANE-CONTIGUOUS 32 B so one i32x8v load fills
//     an aligned 8-reg tuple: [lane(64)][32B] ; k = (lane>>4)*32 + j
#define A8_BYTES ((size_t)64 * KC8 * 8 * 2048)    //  6.29 MB
#define W8_BYTES ((size_t)NBLK * KC8 * 8 * 2048)  // 38.6 MB

// ---------------------------------------------------------------------------
// async global->LDS, 16B per lane (wave-uniform base + lane*16 semantics)
// ---------------------------------------------------------------------------
__device__ __forceinline__ void g2l16(const void* g, void* l) {
    __builtin_amdgcn_global_load_lds(
        (const __attribute__((address_space(1))) unsigned int*)g,
        (__attribute__((address_space(3))) unsigned int*)l,
        16, 0, 0);
}

// ---------------------------------------------------------------------------
// Converters: fp32 -> fp8 e4m3 (OCP), pre-swizzled into MFMA fragment order.
// W additionally scaled by log2(e) so GEMM logits come out base-2.
// Each block handles 128 rows x 64 K-cols (half of a K=128 chunk).
// ---------------------------------------------------------------------------
__global__ __launch_bounds__(256)
void convert_A8_kernel(const float* __restrict__ p2, const float* __restrict__ p3,
                       unsigned char* __restrict__ A8)
{
    __shared__ float Ls[128][65];
    const int mb = blockIdx.x;             // 0..63
    const int kc = blockIdx.y;             // 0..11 (64-col half-chunks)
    const int tid = threadIdx.x;
    const int colBase = kc * 64;

#pragma unroll
    for (int p = 0; p < 8; ++p) {
        int i = p * 1024 + tid * 4;
        int r = i >> 6;
        int c = i & 63;
        int m = mb * 128 + r;
        const float* src = (m < BT) ? (p2 + (size_t)m * KDIM)
                                    : (p3 + (size_t)(m - BT) * KDIM);
        float4 v = *(const float4*)(src + colBase + c);
        Ls[r][c + 0] = v.x; Ls[r][c + 1] = v.y;
        Ls[r][c + 2] = v.z; Ls[r][c + 3] = v.w;
    }
    __syncthreads();

    const int k0 = kc >> 1;
    const int gBase = (kc & 1) * 2;        // lane-group base (0 or 2)
#pragma unroll
    for (int p = 0; p < 2; ++p) {
        int f    = tid + p * 256;          // 0..511
        int tile = f >> 6;
        int r6   = f & 63;
        int lp   = r6 >> 1;                // 0..31
        int h    = r6 & 1;
        int lane = gBase * 16 + lp;        // output lane 0..63
        int row  = tile * 16 + (lp & 15);
        int cloc = (lp >> 4) * 32 + h * 16;
        unsigned int d[4];
#pragma unroll
        for (int q = 0; q < 4; ++q) {
            int dd = 0;
            dd = __builtin_amdgcn_cvt_pk_fp8_f32(Ls[row][cloc + q*4 + 0],
                                                 Ls[row][cloc + q*4 + 1], dd, false);
            dd = __builtin_amdgcn_cvt_pk_fp8_f32(Ls[row][cloc + q*4 + 2],
                                                 Ls[row][cloc + q*4 + 3], dd, true);
            d[q] = (unsigned int)dd;
        }
        // A8: [h][lane][16B] within the 2 KB unit (g2l16-compatible)
        size_t off = ((size_t)(mb * KC8 + k0) * 8 + tile) * 2048
                   + (size_t)h * 1024 + (size_t)lane * 16;
        *(uint4*)(A8 + off) = make_uint4(d[0], d[1], d[2], d[3]);
    }
}

__global__ __launch_bounds__(256)
void convert_W8_kernel(const float* __restrict__ W, unsigned char* __restrict__ W8)
{
    __shared__ float Ls[128][65];
    const int nb = blockIdx.x;             // 0..392
    const int kc = blockIdx.y;             // 0..11
    const int tid = threadIdx.x;
    const int colBase = kc * 64;

#pragma unroll
    for (int p = 0; p < 8; ++p) {
        int i = p * 1024 + tid * 4;
        int r = i >> 6;
        int c = i & 63;
        int v = nb * 128 + r;
        float4 val = make_float4(0.f, 0.f, 0.f, 0.f);
        if (v < VDIM) val = *(const float4*)(W + (size_t)v * KDIM + colBase + c);
        Ls[r][c + 0] = val.x * LOG2E; Ls[r][c + 1] = val.y * LOG2E;
        Ls[r][c + 2] = val.z * LOG2E; Ls[r][c + 3] = val.w * LOG2E;
    }
    __syncthreads();

    const int k0 = kc >> 1;
    const int gBase = (kc & 1) * 2;
#pragma unroll
    for (int p = 0; p < 2; ++p) {
        int f    = tid + p * 256;
        int tile = f >> 6;
        int r6   = f & 63;
        int lp   = r6 >> 1;
        int h    = r6 & 1;
        int lane = gBase * 16 + lp;
        int row  = tile * 16 + (lp & 15);
        int cloc = (lp >> 4) * 32 + h * 16;
        unsigned int d[4];
#pragma unroll
        for (int q = 0; q < 4; ++q) {
            int dd = 0;
            dd = __builtin_amdgcn_cvt_pk_fp8_f32(Ls[row][cloc + q*4 + 0],
                                                 Ls[row][cloc + q*4 + 1], dd, false);
            dd = __builtin_amdgcn_cvt_pk_fp8_f32(Ls[row][cloc + q*4 + 2],
                                                 Ls[row][cloc + q*4 + 3], dd, true);
            d[q] = (unsigned int)dd;
        }
        // W8: LANE-CONTIGUOUS [lane][32B] within the 2 KB unit
        size_t off = ((size_t)(nb * KC8 + k0) * 8 + tile) * 2048
                   + (size_t)lane * 32 + (size_t)h * 16;
        *(uint4*)(W8 + off) = make_uint4(d[0], d[1], d[2], d[3]);
    }
}

// ---------------------------------------------------------------------------
// Main GEMM (fp8 MX, scales = 1.0): 128x128 tile, 256 threads (4 waves 2x2),
// wave tile 64x64, K-chunks of 128 via mfma_scale_f32_16x16x128_f8f6f4.
// Pipe split as the 681us f16 baseline: A via global_load_lds dbuf LDS,
// B direct global->VGPR with next-k0 prefetch.
//
// R6 post-mortem (spill trilogy): WRITE_SIZE byte-identical across R5/R6
// -> spill is set by (demand - granted arch VGPRs), not load shapes.
// Grant pattern: arch VGPRs step in 64-reg granules under the waves_per_eu
// floor: (256,4)->arch 64 (80-reg spill), (256,2)->arch 128 (18-reg spill;
// demand ~145).  Fix: (256,1) lets the allocator take the 192-arch granule
// (total 256 with acc=64) -> zero spill, still 2 waves/SIMD (512-reg SIMD
// pool), still 2 blocks/CU.
// ---------------------------------------------------------------------------
__global__ __launch_bounds__(256, 1)
void gemm_fp8_kernel(const unsigned char* __restrict__ A8,
                     const unsigned char* __restrict__ W8,
                     double* __restrict__ g_sumexp)
{
    __shared__ __align__(16) unsigned char As[2][16384];   // 32 KB
    __shared__ float rowsum[128];

    const int tid  = threadIdx.x;
    const int lane = tid & 63;
    const int w    = tid >> 6;       // 0..3
    const int wm   = w >> 1;         // 0..1
    const int wn   = w & 1;          // 0..1
    const int mb   = blockIdx.x;     // 0..63
    const int nb   = blockIdx.y;     // 0..392

    if (tid < 128) rowsum[tid] = 0.0f;

    f32x4 acc[4][4];
#pragma unroll
    for (int i = 0; i < 4; ++i)
#pragma unroll
        for (int j = 0; j < 4; ++j) acc[i][j] = (f32x4)0.0f;

    const unsigned char* Agl = A8 + (size_t)mb * KC8 * 8 * 2048 + (size_t)lane * 16;
    const unsigned char* Bgl = W8 + ((size_t)nb * KC8 * 8 + (size_t)wn * 4) * 2048
                                  + (size_t)lane * 32;
    unsigned char* sDst = &As[0][0] + (size_t)(2 * w) * 2048 + (size_t)lane * 16;
    const unsigned char* aRd = &As[0][0] + (size_t)(wm * 4) * 2048 + (size_t)lane * 16;

    // wave w stages fragment-units {2w, 2w+1} (4 x g2l16 per wave per k0)
#define STAGE8(k0_, buf_)                                                     \
    {                                                                         \
        _Pragma("unroll")                                                     \
        for (int uu = 0; uu < 2; ++uu)                                        \
            _Pragma("unroll")                                                 \
            for (int hh = 0; hh < 2; ++hh)                                    \
                g2l16(Agl + ((size_t)(k0_) * 8 + 2 * w + uu) * 2048           \
                          + (size_t)hh * 1024,                                \
                      sDst + (size_t)(buf_) * 16384 + (size_t)uu * 2048       \
                           + (size_t)hh * 1024);                              \
    }

    i32x8v b8[4];                         // B fragments, single-load tuples
#define LOADB(k0_)                                                            \
    {                                                                         \
        _Pragma("unroll")                                                     \
        for (int nt = 0; nt < 4; ++nt)                                        \
            b8[nt] = *(const i32x8v*)(Bgl + ((size_t)(k0_) * 8 + nt) * 2048); \
    }

    STAGE8(0, 0);
    LOADB(0);

#pragma unroll
    for (int k0 = 0; k0 < KC8; ++k0) {
        const int buf = k0 & 1;
        __syncthreads();                       // As[buf] + b8[] resident
        if (k0 + 1 < KC8) STAGE8(k0 + 1, buf ^ 1);
#pragma unroll
        for (int tm = 0; tm < 4; ++tm) {
            i32x4v al = *(const i32x4v*)(aRd + (size_t)buf * 16384
                                             + (size_t)tm * 2048);
            i32x4v ah = *(const i32x4v*)(aRd + (size_t)buf * 16384
                                             + (size_t)tm * 2048 + 1024);
            i32x8v a8 = CAT8(al, ah);
#pragma unroll
            for (int nt = 0; nt < 4; ++nt)
                acc[tm][nt] = __builtin_amdgcn_mfma_scale_f32_16x16x128_f8f6f4(
                    a8, b8[nt], acc[tm][nt],
                    0 /*cbsz: A=fp8 e4m3*/, 0 /*blgp: B=fp8 e4m3*/,
                    0, 0x7F7F7F7F /*scale_a = 1.0*/,
                    0, 0x7F7F7F7F /*scale_b = 1.0*/);
        }
        if (k0 + 1 < KC8) LOADB(k0 + 1);       // prefetch next B after last use
    }
#undef STAGE8
#undef LOADB

    // --- epilogue: exp2 (logits pre-scaled by log2e), per-row reduce ---
    __syncthreads();
    const int colBase = nb * 128 + wn * 64;
    const int quad = lane >> 4;
    const int cidx = lane & 15;
#pragma unroll
    for (int tm = 0; tm < 4; ++tm) {
#pragma unroll
        for (int r = 0; r < 4; ++r) {
            float s = 0.0f;
#pragma unroll
            for (int tn = 0; tn < 4; ++tn) {
                int col = colBase + tn * 16 + cidx;
                if (col < VDIM) s += __builtin_amdgcn_exp2f(acc[tm][tn][r]);
            }
            s += __shfl_xor(s, 1);
            s += __shfl_xor(s, 2);
            s += __shfl_xor(s, 4);
            s += __shfl_xor(s, 8);
            if (cidx == 0) {
                int row = wm * 64 + tm * 16 + quad * 4 + r;
                atomicAdd(&rowsum[row], s);
            }
        }
    }
    __syncthreads();
    if (tid < 128) {
        atomicAdd(&g_sumexp[(size_t)mb * 128 + tid], (double)rowsum[tid]);
    }
}

// ---------------------------------------------------------------------------
// Fallback fp32 GEMM (round-2 kernel) if workspace is too small.
// ---------------------------------------------------------------------------
#define BM 128
#define BN 128
#define BK 16
#define LDPAD 4
__global__ __launch_bounds__(256)
void logits_expsum_kernel(const float* __restrict__ p2,
                          const float* __restrict__ p3,
                          const float* __restrict__ W,
                          double* __restrict__ g_sumexp)
{
    __shared__ float As[BK][BM + LDPAD];
    __shared__ float Bsh[BK][BN + LDPAD];
    __shared__ float rowsum[BM];

    const int tid     = threadIdx.x;
    const int rowBase = blockIdx.y * BM;
    const int colBase = blockIdx.x * BN;

    if (tid < BM) rowsum[tid] = 0.0f;

    float acc[8][8];
#pragma unroll
    for (int i = 0; i < 8; ++i)
#pragma unroll
        for (int j = 0; j < 8; ++j) acc[i][j] = 0.0f;

    const int ty = tid >> 4;
    const int tx = tid & 15;
    const int r0 = ty * 8;
    const int c0 = tx * 4;

    for (int k0 = 0; k0 < KDIM; k0 += BK) {
        __syncthreads();
#pragma unroll
        for (int l = 0; l < 2; ++l) {
            int id  = tid + l * 256;
            int row = id >> 2;
            int kq  = id & 3;
            int m   = rowBase + row;
            const float* src = (m < BT) ? (p2 + (size_t)m * KDIM)
                                        : (p3 + (size_t)(m - BT) * KDIM);
            float4 v = *(const float4*)(src + k0 + kq * 4);
            As[kq * 4 + 0][row] = v.x;
            As[kq * 4 + 1][row] = v.y;
            As[kq * 4 + 2][row] = v.z;
            As[kq * 4 + 3][row] = v.w;
        }
#pragma unroll
        for (int l = 0; l < 2; ++l) {
            int id  = tid + l * 256;
            int row = id >> 2;
            int kq  = id & 3;
            int c   = colBase + row;
            int cs  = (c < VDIM) ? c : (VDIM - 1);
            float4 v = *(const float4*)(W + (size_t)cs * KDIM + k0 + kq * 4);
            Bsh[kq * 4 + 0][row] = v.x;
            Bsh[kq * 4 + 1][row] = v.y;
            Bsh[kq * 4 + 2][row] = v.z;
            Bsh[kq * 4 + 3][row] = v.w;
        }
        __syncthreads();
#pragma unroll
        for (int kk = 0; kk < BK; ++kk) {
            float a[8], bb[8];
            *(float4*)&a[0]  = *(const float4*)&As[kk][r0];
            *(float4*)&a[4]  = *(const float4*)&As[kk][r0 + 4];
            *(float4*)&bb[0] = *(const float4*)&Bsh[kk][c0];
            *(float4*)&bb[4] = *(const float4*)&Bsh[kk][64 + c0];
#pragma unroll
            for (int i = 0; i < 8; ++i)
#pragma unroll
                for (int j = 0; j < 8; ++j)
                    acc[i][j] = fmaf(a[i], bb[j], acc[i][j]);
        }
    }

    __syncthreads();
#pragma unroll
    for (int i = 0; i < 8; ++i) {
        float s = 0.0f;
#pragma unroll
        for (int j = 0; j < 8; ++j) {
            int c = colBase + ((j < 4) ? (c0 + j) : (64 + c0 + (j - 4)));
            if (c < VDIM) s += expf(acc[i][j]);
        }
        atomicAdd(&rowsum[r0 + i], s);
    }
    __syncthreads();
    if (tid < BM) {
        atomicAdd(&g_sumexp[rowBase + tid], (double)rowsum[tid]);
    }
}

// ---------------------------------------------------------------------------
// Kernel 2: per token — exact fp32 target logits + cosine.  NO atomics:
// writes per-token values; reduced by final_scalar_kernel.
// tokvals[t] = {nll2, nll3, cos, valid}
// ---------------------------------------------------------------------------
__global__ __launch_bounds__(256)
void finalize_tokens_kernel(const float* __restrict__ p2,
                            const float* __restrict__ p3,
                            const float* __restrict__ W,
                            const int*   __restrict__ targets,
                            const double* __restrict__ g_sumexp,
                            double* __restrict__ tokvals)
{
    const int t   = blockIdx.x;
    const int tid = threadIdx.x;
    const int tg  = targets[t];
    const bool valid = (tg >= 0);
    const float* w = W + (size_t)(valid ? tg : 0) * KDIM;
    const float* a = p2 + (size_t)t * KDIM;
    const float* b = p3 + (size_t)t * KDIM;

    float s22 = 0.f, s33 = 0.f, s23 = 0.f, s2w = 0.f, s3w = 0.f;
    for (int i = tid; i < KDIM; i += 256) {
        float x = a[i], y = b[i], ww = w[i];
        s22 = fmaf(x, x, s22);
        s33 = fmaf(y, y, s33);
        s23 = fmaf(x, y, s23);
        s2w = fmaf(x, ww, s2w);
        s3w = fmaf(y, ww, s3w);
    }
#pragma unroll
    for (int off = 32; off > 0; off >>= 1) {
        s22 += __shfl_down(s22, off);
        s33 += __shfl_down(s33, off);
        s23 += __shfl_down(s23, off);
        s2w += __shfl_down(s2w, off);
        s3w += __shfl_down(s3w, off);
    }
    __shared__ float sm[5][4];
    const int wv = tid >> 6, lane = tid & 63;
    if (lane == 0) {
        sm[0][wv] = s22; sm[1][wv] = s33; sm[2][wv] = s23;
        sm[3][wv] = s2w; sm[4][wv] = s3w;
    }
    __syncthreads();
    if (tid == 0) {
        float S22 = sm[0][0] + sm[0][1] + sm[0][2] + sm[0][3];
        float S33 = sm[1][0] + sm[1][1] + sm[1][2] + sm[1][3];
        float S23 = sm[2][0] + sm[2][1] + sm[2][2] + sm[2][3];
        float S2w = sm[3][0] + sm[3][1] + sm[3][2] + sm[3][3];
        float S3w = sm[4][0] + sm[4][1] + sm[4][2] + sm[4][3];

        float n2 = fmaxf(sqrtf(S22), EPS_COS);
        float n3 = fmaxf(sqrtf(S33), EPS_COS);

        double4 out;
        out.x = valid ? (log(g_sumexp[t])      - (double)S2w) : 0.0;
        out.y = valid ? (log(g_sumexp[BT + t]) - (double)S3w) : 0.0;
        out.z = (double)(S23 / (n2 * n3));
        out.w = valid ? 1.0 : 0.0;
        *(double4*)(tokvals + 4 * (size_t)t) = out;
    }
}

// ---------------------------------------------------------------------------
// Kernel 3: reduce tokvals -> output scalar (one 1024-thread block).
// ---------------------------------------------------------------------------
__global__ __launch_bounds__(1024)
void final_scalar_kernel(const double* __restrict__ tokvals,
                         float* __restrict__ out)
{
    const int tid = threadIdx.x;
    double s0 = 0.0, s1 = 0.0, s2 = 0.0, s3 = 0.0;
    for (int t = tid; t < BT; t += 1024) {
        double4 v = *(const double4*)(tokvals + 4 * (size_t)t);
        s0 += v.x; s1 += v.y; s2 += v.z; s3 += v.w;
    }
#pragma unroll
    for (int off = 32; off > 0; off >>= 1) {
        s0 += __shfl_down(s0, off);
        s1 += __shfl_down(s1, off);
        s2 += __shfl_down(s2, off);
        s3 += __shfl_down(s3, off);
    }
    __shared__ double sm[4][16];
    const int wv = tid >> 6, lane = tid & 63;
    if (lane == 0) { sm[0][wv] = s0; sm[1][wv] = s1; sm[2][wv] = s2; sm[3][wv] = s3; }
    __syncthreads();
    if (tid == 0) {
        double S0 = 0, S1 = 0, S2 = 0, S3 = 0;
#pragma unroll
        for (int i = 0; i < 16; ++i) { S0 += sm[0][i]; S1 += sm[1][i]; S2 += sm[2][i]; S3 += sm[3][i]; }
        double cnt = (S3 > 0.0) ? S3 : 1.0;
        double loss_p2 = S0 / cnt;
        double loss_p3 = S1 / cnt;
        double reward_loss = -REWARD_SCALE * (loss_p2 - loss_p3);
        double divergence  =  DIV_WEIGHT * (S2 / (double)BT);
        out[0] = (float)(reward_loss + divergence);
    }
}

// ---------------------------------------------------------------------------
extern "C" void kernel_launch(void* const* d_in, const int* in_sizes, int n_in,
                              void* d_out, int out_size, void* d_ws, size_t ws_size,
                              hipStream_t stream)
{
    const float* p2  = (const float*)d_in[0];   // [2,2048,768] fp32
    const float* p3  = (const float*)d_in[1];   // [2,2048,768] fp32
    const float* W   = (const float*)d_in[2];   // [50257,768] fp32
    const int*   tgt = (const int*)d_in[3];     // [2,2048]

    double* g_sumexp = (double*)d_ws;                    // 8192 doubles (64 KB)
    double* tokvals  = g_sumexp + M_TOT;                 // 16384 doubles (128 KB)
    char*   fragbase = (char*)d_ws + 196608;

    hipMemsetAsync(d_ws, 0, 65536, stream);   // g_sumexp only

    const size_t need = 196608 + A8_BYTES + W8_BYTES;    // ~45 MB
    if (ws_size >= need) {
        unsigned char* A8 = (unsigned char*)fragbase;
        unsigned char* W8 = A8 + A8_BYTES;

        convert_A8_kernel<<<dim3(64, 12), dim3(256), 0, stream>>>(p2, p3, A8);
        convert_W8_kernel<<<dim3(NBLK, 12), dim3(256), 0, stream>>>(W, W8);
        // grid.x = mb fast: consecutive blocks share nb (B panel L2-hot)
        // and span mb (A slices small, L2-resident everywhere).
        gemm_fp8_kernel<<<dim3(64, NBLK), dim3(256), 0, stream>>>(A8, W8, g_sumexp);
    } else {
        logits_expsum_kernel<<<dim3(NBLK, 64), dim3(256), 0, stream>>>(p2, p3, W, g_sumexp);
    }

    finalize_tokens_kernel<<<dim3(BT), dim3(256), 0, stream>>>(
        p2, p3, W, tgt, g_sumexp, tokvals);

    final_scalar_kernel<<<dim3(1), dim3(1024), 0, stream>>>(tokvals, (float*)d_out);
}